// Round 1
// baseline (2402.115 us; speedup 1.0000x reference)
//
#include <hip/hip_runtime.h>
#include <hip/hip_bf16.h>
#include <cstddef>

#define D256 256

// ---------------- GEMM: out = act( A@B (+ A2@B2) + bias ) ----------------
// A [M,256] f32 row-major, B [256,256] f32 row-major, out [M,256]
// 64x64 tile per block (256 threads), 4x4 micro-tile per thread, BK=16.
template<int DUAL, int RELU>
__global__ __launch_bounds__(256)
void gemm_kernel(const float* __restrict__ A, const float* __restrict__ B,
                 const float* __restrict__ A2, const float* __restrict__ B2,
                 const float* __restrict__ bias, float* __restrict__ out, int M)
{
    __shared__ float As[16][64];   // [k][m]
    __shared__ float Bs[16][64];   // [k][n]
    const int t  = threadIdx.x;
    const int m0 = blockIdx.x * 64;
    const int n0 = blockIdx.y * 64;
    const int tm = t & 15;          // micro-tile row group
    const int tn = t >> 4;          // micro-tile col group

    float acc[4][4];
#pragma unroll
    for (int i = 0; i < 4; ++i)
#pragma unroll
        for (int j = 0; j < 4; ++j) acc[i][j] = 0.0f;

    const int lr = t >> 2;          // A-tile row 0..63
    const int lk = (t & 3) << 2;    // A-tile k offset 0,4,8,12
    const int br = t >> 4;          // B-tile k row 0..15
    const int bc = (t & 15) << 2;   // B-tile col offset

    const int npass = DUAL ? 2 : 1;
    for (int pass = 0; pass < npass; ++pass) {
        const float* __restrict__ Ap = (DUAL && pass) ? A2 : A;
        const float* __restrict__ Bp = (DUAL && pass) ? B2 : B;
        for (int k0 = 0; k0 < D256; k0 += 16) {
            __syncthreads();
            const int arow = m0 + lr;
            float4 av = make_float4(0.f, 0.f, 0.f, 0.f);
            if (arow < M)
                av = *(const float4*)(Ap + (size_t)arow * D256 + k0 + lk);
            As[lk + 0][lr] = av.x;
            As[lk + 1][lr] = av.y;
            As[lk + 2][lr] = av.z;
            As[lk + 3][lr] = av.w;
            const float4 bv = *(const float4*)(Bp + (size_t)(k0 + br) * D256 + n0 + bc);
            *(float4*)&Bs[br][bc] = bv;
            __syncthreads();
#pragma unroll
            for (int kk = 0; kk < 16; ++kk) {
                const float4 a = *(const float4*)&As[kk][tm << 2];
                const float4 b = *(const float4*)&Bs[kk][tn << 2];
                acc[0][0] = fmaf(a.x, b.x, acc[0][0]);
                acc[0][1] = fmaf(a.x, b.y, acc[0][1]);
                acc[0][2] = fmaf(a.x, b.z, acc[0][2]);
                acc[0][3] = fmaf(a.x, b.w, acc[0][3]);
                acc[1][0] = fmaf(a.y, b.x, acc[1][0]);
                acc[1][1] = fmaf(a.y, b.y, acc[1][1]);
                acc[1][2] = fmaf(a.y, b.z, acc[1][2]);
                acc[1][3] = fmaf(a.y, b.w, acc[1][3]);
                acc[2][0] = fmaf(a.z, b.x, acc[2][0]);
                acc[2][1] = fmaf(a.z, b.y, acc[2][1]);
                acc[2][2] = fmaf(a.z, b.z, acc[2][2]);
                acc[2][3] = fmaf(a.z, b.w, acc[2][3]);
                acc[3][0] = fmaf(a.w, b.x, acc[3][0]);
                acc[3][1] = fmaf(a.w, b.y, acc[3][1]);
                acc[3][2] = fmaf(a.w, b.z, acc[3][2]);
                acc[3][3] = fmaf(a.w, b.w, acc[3][3]);
            }
        }
    }

    const float4 bb = *(const float4*)(bias + n0 + (tn << 2));
#pragma unroll
    for (int i = 0; i < 4; ++i) {
        const int row = m0 + (tm << 2) + i;
        if (row < M) {
            float4 o;
            o.x = acc[i][0] + bb.x;
            o.y = acc[i][1] + bb.y;
            o.z = acc[i][2] + bb.z;
            o.w = acc[i][3] + bb.w;
            if (RELU) {
                o.x = fmaxf(o.x, 0.f); o.y = fmaxf(o.y, 0.f);
                o.z = fmaxf(o.z, 0.f); o.w = fmaxf(o.w, 0.f);
            }
            *(float4*)(out + (size_t)row * D256 + n0 + (tn << 2)) = o;
        }
    }
}

// ------------- edge-parallel segment-max scatter (one wave per edge) -------------
// m values are relu outputs (>= 0), so uint compare == float compare, and
// 0-initialized agg is the correct identity (also handles zero in-degree).
__global__ __launch_bounds__(256)
void scatter_max_kernel(const int* __restrict__ src, const int* __restrict__ dst,
                        const float* __restrict__ m, unsigned int* __restrict__ agg,
                        int E)
{
    const int wid  = (int)(((size_t)blockIdx.x * 256 + threadIdx.x) >> 6);
    const int lane = threadIdx.x & 63;
    if (wid >= E) return;
    const int s = src[wid];
    const int d = dst[wid];
    const float4 v = *(const float4*)(m + (size_t)s * D256 + (lane << 2));
    unsigned int* a = agg + (size_t)d * D256 + (lane << 2);
    const uint4 cur = *(const uint4*)a;   // monotone lattice: stale read <= actual, skip is safe
    const unsigned u0 = __float_as_uint(v.x);
    const unsigned u1 = __float_as_uint(v.y);
    const unsigned u2 = __float_as_uint(v.z);
    const unsigned u3 = __float_as_uint(v.w);
    if (u0 > cur.x) atomicMax(a + 0, u0);
    if (u1 > cur.y) atomicMax(a + 1, u1);
    if (u2 > cur.z) atomicMax(a + 2, u2);
    if (u3 > cur.w) atomicMax(a + 3, u3);
}

// ------------- row-wise L2 normalize (one wave per row) -------------
__global__ __launch_bounds__(256)
void l2norm_kernel(const float* __restrict__ in, float* __restrict__ outp, int M)
{
    const int wid  = (int)(((size_t)blockIdx.x * 256 + threadIdx.x) >> 6);
    const int lane = threadIdx.x & 63;
    if (wid >= M) return;
    const float4 v = *(const float4*)(in + (size_t)wid * D256 + (lane << 2));
    float ss = v.x * v.x + v.y * v.y + v.z * v.z + v.w * v.w;
#pragma unroll
    for (int o = 32; o >= 1; o >>= 1) ss += __shfl_xor(ss, o);
    const float n   = sqrtf(ss);
    const float inv = 1.0f / fmaxf(n, 1e-12f);
    float4 o4;
    o4.x = v.x * inv; o4.y = v.y * inv; o4.z = v.z * inv; o4.w = v.w * inv;
    *(float4*)(outp + (size_t)wid * D256 + (lane << 2)) = o4;
}

extern "C" void kernel_launch(void* const* d_in, const int* in_sizes, int n_in,
                              void* d_out, int out_size, void* d_ws, size_t ws_size,
                              hipStream_t stream)
{
    const float* x        = (const float*)d_in[0];
    const int*   src      = (const int*)  d_in[1];
    const int*   dst      = (const int*)  d_in[2];
    const float* W_pool0  = (const float*)d_in[3];
    const float* b_pool0  = (const float*)d_in[4];
    const float* W_self0  = (const float*)d_in[5];
    const float* W_neigh0 = (const float*)d_in[6];
    const float* b0       = (const float*)d_in[7];
    const float* W_pool1  = (const float*)d_in[8];
    const float* b_pool1  = (const float*)d_in[9];
    const float* W_self1  = (const float*)d_in[10];
    const float* W_neigh1 = (const float*)d_in[11];
    const float* b1       = (const float*)d_in[12];

    const int N = in_sizes[0] / D256;
    const int E = in_sizes[1];

    float* h1  = (float*)d_out;                       // [N,256] layer-1 output
    float* enc = (float*)d_out + (size_t)N * D256;    // [N,256] enc_feat_input

    float* m   = (float*)d_ws;                        // [N,256] pool msgs / combine tmp
    float* agg = m + (size_t)N * D256;                // [N,256] segment-max accumulator

    const dim3 gemm_grid((N + 63) / 64, 4);
    const int  scatter_blocks = (E + 3) / 4;
    const int  norm_blocks    = (N + 3) / 4;
    const size_t agg_bytes = (size_t)N * D256 * sizeof(float);

    // ---------------- layer 0 ----------------
    hipMemsetAsync(agg, 0, agg_bytes, stream);
    gemm_kernel<0,1><<<gemm_grid, 256, 0, stream>>>(x, W_pool0, nullptr, nullptr,
                                                    b_pool0, m, N);
    scatter_max_kernel<<<scatter_blocks, 256, 0, stream>>>(src, dst, m,
                                                           (unsigned int*)agg, E);
    // tmp (reuse m): relu(x@W_self0 + agg@W_neigh0 + b0)
    gemm_kernel<1,1><<<gemm_grid, 256, 0, stream>>>(x, W_self0, agg, W_neigh0,
                                                    b0, m, N);
    l2norm_kernel<<<norm_blocks, 256, 0, stream>>>(m, enc, N);

    // ---------------- layer 1 ----------------
    hipMemsetAsync(agg, 0, agg_bytes, stream);
    gemm_kernel<0,1><<<gemm_grid, 256, 0, stream>>>(enc, W_pool1, nullptr, nullptr,
                                                    b_pool1, m, N);
    scatter_max_kernel<<<scatter_blocks, 256, 0, stream>>>(src, dst, m,
                                                           (unsigned int*)agg, E);
    gemm_kernel<1,0><<<gemm_grid, 256, 0, stream>>>(enc, W_self1, agg, W_neigh1,
                                                    b1, h1, N);
}

// Round 2
// 1010.216 us; speedup vs baseline: 2.3778x; 2.3778x over previous
//
#include <hip/hip_runtime.h>
#include <hip/hip_bf16.h>
#include <cstddef>

#define D256 256

// ---------------- GEMM: out = act( A@B (+ A2@B2) + bias ) ----------------
// A [M,256] f32 row-major, B [256,256] f32 row-major, out [M,256]
// 64x64 tile per block (256 threads), 4x4 micro-tile per thread, BK=16.
template<int DUAL, int RELU>
__global__ __launch_bounds__(256)
void gemm_kernel(const float* __restrict__ A, const float* __restrict__ B,
                 const float* __restrict__ A2, const float* __restrict__ B2,
                 const float* __restrict__ bias, float* __restrict__ out, int M)
{
    __shared__ float As[16][64];   // [k][m]
    __shared__ float Bs[16][64];   // [k][n]
    const int t  = threadIdx.x;
    const int m0 = blockIdx.x * 64;
    const int n0 = blockIdx.y * 64;
    const int tm = t & 15;          // micro-tile row group
    const int tn = t >> 4;          // micro-tile col group

    float acc[4][4];
#pragma unroll
    for (int i = 0; i < 4; ++i)
#pragma unroll
        for (int j = 0; j < 4; ++j) acc[i][j] = 0.0f;

    const int lr = t >> 2;          // A-tile row 0..63
    const int lk = (t & 3) << 2;    // A-tile k offset 0,4,8,12
    const int br = t >> 4;          // B-tile k row 0..15
    const int bc = (t & 15) << 2;   // B-tile col offset

    const int npass = DUAL ? 2 : 1;
    for (int pass = 0; pass < npass; ++pass) {
        const float* __restrict__ Ap = (DUAL && pass) ? A2 : A;
        const float* __restrict__ Bp = (DUAL && pass) ? B2 : B;
        for (int k0 = 0; k0 < D256; k0 += 16) {
            __syncthreads();
            const int arow = m0 + lr;
            float4 av = make_float4(0.f, 0.f, 0.f, 0.f);
            if (arow < M)
                av = *(const float4*)(Ap + (size_t)arow * D256 + k0 + lk);
            As[lk + 0][lr] = av.x;
            As[lk + 1][lr] = av.y;
            As[lk + 2][lr] = av.z;
            As[lk + 3][lr] = av.w;
            const float4 bv = *(const float4*)(Bp + (size_t)(k0 + br) * D256 + n0 + bc);
            *(float4*)&Bs[br][bc] = bv;
            __syncthreads();
#pragma unroll
            for (int kk = 0; kk < 16; ++kk) {
                const float4 a = *(const float4*)&As[kk][tm << 2];
                const float4 b = *(const float4*)&Bs[kk][tn << 2];
                acc[0][0] = fmaf(a.x, b.x, acc[0][0]);
                acc[0][1] = fmaf(a.x, b.y, acc[0][1]);
                acc[0][2] = fmaf(a.x, b.z, acc[0][2]);
                acc[0][3] = fmaf(a.x, b.w, acc[0][3]);
                acc[1][0] = fmaf(a.y, b.x, acc[1][0]);
                acc[1][1] = fmaf(a.y, b.y, acc[1][1]);
                acc[1][2] = fmaf(a.y, b.z, acc[1][2]);
                acc[1][3] = fmaf(a.y, b.w, acc[1][3]);
                acc[2][0] = fmaf(a.z, b.x, acc[2][0]);
                acc[2][1] = fmaf(a.z, b.y, acc[2][1]);
                acc[2][2] = fmaf(a.z, b.z, acc[2][2]);
                acc[2][3] = fmaf(a.z, b.w, acc[2][3]);
                acc[3][0] = fmaf(a.w, b.x, acc[3][0]);
                acc[3][1] = fmaf(a.w, b.y, acc[3][1]);
                acc[3][2] = fmaf(a.w, b.z, acc[3][2]);
                acc[3][3] = fmaf(a.w, b.w, acc[3][3]);
            }
        }
    }

    const float4 bb = *(const float4*)(bias + n0 + (tn << 2));
#pragma unroll
    for (int i = 0; i < 4; ++i) {
        const int row = m0 + (tm << 2) + i;
        if (row < M) {
            float4 o;
            o.x = acc[i][0] + bb.x;
            o.y = acc[i][1] + bb.y;
            o.z = acc[i][2] + bb.z;
            o.w = acc[i][3] + bb.w;
            if (RELU) {
                o.x = fmaxf(o.x, 0.f); o.y = fmaxf(o.y, 0.f);
                o.z = fmaxf(o.z, 0.f); o.w = fmaxf(o.w, 0.f);
            }
            *(float4*)(out + (size_t)row * D256 + n0 + (tn << 2)) = o;
        }
    }
}

// ---------------- CSR build: histogram -> scan -> bucket scatter ----------------
__global__ __launch_bounds__(256)
void hist_kernel(const int* __restrict__ dst, int* __restrict__ deg, int E)
{
    const int stride = gridDim.x * 256;
    for (int e = blockIdx.x * 256 + threadIdx.x; e < E; e += stride)
        atomicAdd(&deg[dst[e]], 1);
}

// single-block exclusive scan over deg[0..N) -> row_ptr[0..N], cursor copy
__global__ __launch_bounds__(1024)
void scan_kernel(const int* __restrict__ deg, int* __restrict__ row_ptr,
                 int* __restrict__ cursor, int N)
{
    __shared__ int smem[1024];
    __shared__ int carry_s;
    if (threadIdx.x == 0) carry_s = 0;
    __syncthreads();
    for (int base = 0; base < N; base += 1024) {
        const int i = base + (int)threadIdx.x;
        const int v = (i < N) ? deg[i] : 0;
        smem[threadIdx.x] = v;
        __syncthreads();
#pragma unroll
        for (int off = 1; off < 1024; off <<= 1) {
            const int t = (threadIdx.x >= (unsigned)off) ? smem[threadIdx.x - off] : 0;
            __syncthreads();
            smem[threadIdx.x] += t;
            __syncthreads();
        }
        const int excl = smem[threadIdx.x] - v;
        const int carry = carry_s;
        if (i < N) {
            row_ptr[i] = carry + excl;
            cursor[i]  = carry + excl;
        }
        const int total = smem[1023];
        __syncthreads();
        if (threadIdx.x == 0) carry_s = carry + total;
        __syncthreads();
    }
    if (threadIdx.x == 0) row_ptr[N] = carry_s;
}

__global__ __launch_bounds__(256)
void bucket_kernel(const int* __restrict__ src, const int* __restrict__ dst,
                   int* __restrict__ cursor, int* __restrict__ esrc, int E)
{
    const int stride = gridDim.x * 256;
    for (int e = blockIdx.x * 256 + threadIdx.x; e < E; e += stride) {
        const int p = atomicAdd(&cursor[dst[e]], 1);
        esrc[p] = src[e];
    }
}

// ---------------- node-parallel segment max (one wave per node) ----------------
// m >= 0 (relu output), accumulator 0 handles zero in-degree exactly.
__global__ __launch_bounds__(256)
void agg_max_kernel(const int* __restrict__ row_ptr, const int* __restrict__ esrc,
                    const float* __restrict__ m, float* __restrict__ agg, int N)
{
    const int wid  = (int)(((size_t)blockIdx.x * 256 + threadIdx.x) >> 6);
    const int lane = threadIdx.x & 63;
    if (wid >= N) return;
    const int beg = row_ptr[wid];
    const int end = row_ptr[wid + 1];
    float4 acc = make_float4(0.f, 0.f, 0.f, 0.f);
    int e = beg;
    for (; e + 1 < end; e += 2) {   // 2-deep for load pipelining
        const int s0 = esrc[e];
        const int s1 = esrc[e + 1];
        const float4 v0 = *(const float4*)(m + (size_t)s0 * D256 + (lane << 2));
        const float4 v1 = *(const float4*)(m + (size_t)s1 * D256 + (lane << 2));
        acc.x = fmaxf(acc.x, fmaxf(v0.x, v1.x));
        acc.y = fmaxf(acc.y, fmaxf(v0.y, v1.y));
        acc.z = fmaxf(acc.z, fmaxf(v0.z, v1.z));
        acc.w = fmaxf(acc.w, fmaxf(v0.w, v1.w));
    }
    if (e < end) {
        const int s0 = esrc[e];
        const float4 v0 = *(const float4*)(m + (size_t)s0 * D256 + (lane << 2));
        acc.x = fmaxf(acc.x, v0.x);
        acc.y = fmaxf(acc.y, v0.y);
        acc.z = fmaxf(acc.z, v0.z);
        acc.w = fmaxf(acc.w, v0.w);
    }
    *(float4*)(agg + (size_t)wid * D256 + (lane << 2)) = acc;
}

// ------------- row-wise L2 normalize (one wave per row) -------------
__global__ __launch_bounds__(256)
void l2norm_kernel(const float* __restrict__ in, float* __restrict__ outp, int M)
{
    const int wid  = (int)(((size_t)blockIdx.x * 256 + threadIdx.x) >> 6);
    const int lane = threadIdx.x & 63;
    if (wid >= M) return;
    const float4 v = *(const float4*)(in + (size_t)wid * D256 + (lane << 2));
    float ss = v.x * v.x + v.y * v.y + v.z * v.z + v.w * v.w;
#pragma unroll
    for (int o = 32; o >= 1; o >>= 1) ss += __shfl_xor(ss, o);
    const float n   = sqrtf(ss);
    const float inv = 1.0f / fmaxf(n, 1e-12f);
    float4 o4;
    o4.x = v.x * inv; o4.y = v.y * inv; o4.z = v.z * inv; o4.w = v.w * inv;
    *(float4*)(outp + (size_t)wid * D256 + (lane << 2)) = o4;
}

extern "C" void kernel_launch(void* const* d_in, const int* in_sizes, int n_in,
                              void* d_out, int out_size, void* d_ws, size_t ws_size,
                              hipStream_t stream)
{
    const float* x        = (const float*)d_in[0];
    const int*   src      = (const int*)  d_in[1];
    const int*   dst      = (const int*)  d_in[2];
    const float* W_pool0  = (const float*)d_in[3];
    const float* b_pool0  = (const float*)d_in[4];
    const float* W_self0  = (const float*)d_in[5];
    const float* W_neigh0 = (const float*)d_in[6];
    const float* b0       = (const float*)d_in[7];
    const float* W_pool1  = (const float*)d_in[8];
    const float* b_pool1  = (const float*)d_in[9];
    const float* W_self1  = (const float*)d_in[10];
    const float* W_neigh1 = (const float*)d_in[11];
    const float* b1       = (const float*)d_in[12];

    const int N = in_sizes[0] / D256;
    const int E = in_sizes[1];

    float* h1  = (float*)d_out;                       // [N,256] layer-1 output
    float* enc = (float*)d_out + (size_t)N * D256;    // [N,256] enc_feat_input

    float* m       = (float*)d_ws;                    // [N,256]
    float* agg     = m + (size_t)N * D256;            // [N,256]
    int*   row_ptr = (int*)(agg + (size_t)N * D256);  // N+1
    int*   cursor  = row_ptr + (N + 1);               // N
    int*   deg     = cursor + N;                      // N
    int*   esrc    = deg + N;                         // E

    const dim3 gemm_grid((N + 63) / 64, 4);
    const int  edge_blocks = (E + 255) / 256 < 2048 ? (E + 255) / 256 : 2048;
    const int  node_blocks = (N + 3) / 4;

    // ---------------- CSR build (src/dst shared by both layers) ----------------
    hipMemsetAsync(deg, 0, (size_t)N * sizeof(int), stream);
    hist_kernel<<<edge_blocks, 256, 0, stream>>>(dst, deg, E);
    scan_kernel<<<1, 1024, 0, stream>>>(deg, row_ptr, cursor, N);
    bucket_kernel<<<edge_blocks, 256, 0, stream>>>(src, dst, cursor, esrc, E);

    // ---------------- layer 0 ----------------
    gemm_kernel<0,1><<<gemm_grid, 256, 0, stream>>>(x, W_pool0, nullptr, nullptr,
                                                    b_pool0, m, N);
    agg_max_kernel<<<node_blocks, 256, 0, stream>>>(row_ptr, esrc, m, agg, N);
    gemm_kernel<1,1><<<gemm_grid, 256, 0, stream>>>(x, W_self0, agg, W_neigh0,
                                                    b0, m, N);
    l2norm_kernel<<<node_blocks, 256, 0, stream>>>(m, enc, N);

    // ---------------- layer 1 ----------------
    gemm_kernel<0,1><<<gemm_grid, 256, 0, stream>>>(enc, W_pool1, nullptr, nullptr,
                                                    b_pool1, m, N);
    agg_max_kernel<<<node_blocks, 256, 0, stream>>>(row_ptr, esrc, m, agg, N);
    gemm_kernel<1,0><<<gemm_grid, 256, 0, stream>>>(enc, W_self1, agg, W_neigh1,
                                                    b1, h1, N);
}

// Round 3
// 518.384 us; speedup vs baseline: 4.6339x; 1.9488x over previous
//
#include <hip/hip_runtime.h>
#include <cstddef>

#define D256 256

typedef __attribute__((ext_vector_type(8))) short bf16x8;
typedef __attribute__((ext_vector_type(4))) float f32x4;

__device__ __forceinline__ ushort f2bf(float f) {
    unsigned u = __float_as_uint(f);
    return (ushort)((u + 0x7FFFu + ((u >> 16) & 1u)) >> 16);   // RNE
}
__device__ __forceinline__ ushort umax16(ushort a, ushort b) { return a > b ? a : b; }

// ---------------- MFMA GEMM: out = act( A@Bt^T (+ A2@Bt2^T) + bias ) ----------------
// A [M,256] bf16 row-major; Bt [256,256] bf16 = W^T (row n = output col, K-contiguous).
// 128x128 tile, 4 waves, 64x64 per wave, BK=32, 16x16x32 MFMA.
// LDS rows padded to 40 ushorts (80B) -> conflict-free ds_read_b128 at row-stride access.
template<int DUAL, int RELU, int OUT_BF16>
__global__ __launch_bounds__(256)
void mfma_gemm_kernel(const ushort* __restrict__ A, const ushort* __restrict__ Bt,
                      const ushort* __restrict__ A2, const ushort* __restrict__ Bt2,
                      const float* __restrict__ bias, void* __restrict__ outp, int M)
{
    __shared__ ushort As[128 * 40];
    __shared__ ushort Bs[128 * 40];
    const int t    = threadIdx.x;
    const int m0   = blockIdx.x * 128;
    const int n0   = blockIdx.y * 128;
    const int lane = t & 63;
    const int wave = t >> 6;
    const int wr   = (wave >> 1) * 64;   // wave's row base within tile
    const int wc   = (wave & 1) * 64;    // wave's col base within tile
    const int lr   = lane & 15;
    const int kg   = lane >> 4;          // k-group 0..3
    const int srow = t >> 2;             // staging row 0..63
    const int sch  = t & 3;              // staging 16B chunk 0..3

    f32x4 acc[4][4];
#pragma unroll
    for (int i = 0; i < 4; ++i)
#pragma unroll
        for (int j = 0; j < 4; ++j) acc[i][j] = (f32x4)(0.0f);

    const int npass = DUAL ? 2 : 1;
    for (int pass = 0; pass < npass; ++pass) {
        const ushort* __restrict__ Ap = (DUAL && pass) ? A2 : A;
        const ushort* __restrict__ Bp = (DUAL && pass) ? Bt2 : Bt;
        for (int k0 = 0; k0 < D256; k0 += 32) {
            __syncthreads();
#pragma unroll
            for (int rep = 0; rep < 2; ++rep) {
                const int row  = rep * 64 + srow;
                const int grow = m0 + row;
                uint4 av = make_uint4(0, 0, 0, 0);
                if (grow < M)
                    av = *(const uint4*)(Ap + (size_t)grow * D256 + k0 + sch * 8);
                *(uint4*)&As[row * 40 + sch * 8] = av;
                const uint4 bv = *(const uint4*)(Bp + (size_t)(n0 + row) * D256 + k0 + sch * 8);
                *(uint4*)&Bs[row * 40 + sch * 8] = bv;
            }
            __syncthreads();
            bf16x8 af[4], bfr[4];
#pragma unroll
            for (int mi = 0; mi < 4; ++mi)
                af[mi] = *(const bf16x8*)&As[(wr + mi * 16 + lr) * 40 + kg * 8];
#pragma unroll
            for (int ni = 0; ni < 4; ++ni)
                bfr[ni] = *(const bf16x8*)&Bs[(wc + ni * 16 + lr) * 40 + kg * 8];
#pragma unroll
            for (int mi = 0; mi < 4; ++mi)
#pragma unroll
                for (int ni = 0; ni < 4; ++ni)
                    acc[mi][ni] = __builtin_amdgcn_mfma_f32_16x16x32_bf16(
                        af[mi], bfr[ni], acc[mi][ni], 0, 0, 0);
        }
    }

    // C/D layout: col = lane&15, row = (lane>>4)*4 + j   [m89-verified]
#pragma unroll
    for (int ni = 0; ni < 4; ++ni) {
        const int col = n0 + wc + ni * 16 + lr;
        const float bb = bias[col];
#pragma unroll
        for (int mi = 0; mi < 4; ++mi) {
            const int rbase = m0 + wr + mi * 16 + kg * 4;
#pragma unroll
            for (int j = 0; j < 4; ++j) {
                const int row = rbase + j;
                if (row < M) {
                    float v = acc[mi][ni][j] + bb;
                    if (RELU) v = fmaxf(v, 0.0f);
                    if (OUT_BF16)
                        ((ushort*)outp)[(size_t)row * D256 + col] = f2bf(v);
                    else
                        ((float*)outp)[(size_t)row * D256 + col] = v;
                }
            }
        }
    }
}

// ---------------- fp32 -> bf16 convert ----------------
__global__ __launch_bounds__(256)
void f2bf_kernel(const float* __restrict__ in, ushort* __restrict__ out, int n4)
{
    const int i = blockIdx.x * 256 + threadIdx.x;
    if (i >= n4) return;
    const float4 v = ((const float4*)in)[i];
    ushort4 o;
    o.x = f2bf(v.x); o.y = f2bf(v.y); o.z = f2bf(v.z); o.w = f2bf(v.w);
    ((ushort4*)out)[i] = o;
}

// ---------------- weight transpose+convert: Bt[n][k] = bf16(W[k][n]) ----------------
struct WP  { const float* w; ushort* o; };
struct WP6 { WP p[6]; };
__global__ __launch_bounds__(256)
void wtrans_kernel(WP6 ps)
{
    const float* __restrict__ W = ps.p[blockIdx.z].w;
    ushort* __restrict__ O      = ps.p[blockIdx.z].o;
    __shared__ float sm[32][33];
    const int tx = threadIdx.x & 31, ty = threadIdx.x >> 5;
    const int k0 = blockIdx.x * 32, n0 = blockIdx.y * 32;
#pragma unroll
    for (int i = 0; i < 4; ++i)
        sm[ty + i * 8][tx] = W[(size_t)(k0 + ty + i * 8) * D256 + n0 + tx];
    __syncthreads();
#pragma unroll
    for (int i = 0; i < 4; ++i)
        O[(size_t)(n0 + ty + i * 8) * D256 + k0 + tx] = f2bf(sm[tx][ty + i * 8]);
}

// ---------------- CSR build: histogram -> scan -> bucket scatter ----------------
__global__ __launch_bounds__(256)
void hist_kernel(const int* __restrict__ dst, int* __restrict__ deg, int E)
{
    const int stride = gridDim.x * 256;
    for (int e = blockIdx.x * 256 + threadIdx.x; e < E; e += stride)
        atomicAdd(&deg[dst[e]], 1);
}

__global__ __launch_bounds__(1024)
void scan_kernel(const int* __restrict__ deg, int* __restrict__ row_ptr,
                 int* __restrict__ cursor, int N)
{
    __shared__ int smem[1024];
    __shared__ int carry_s;
    if (threadIdx.x == 0) carry_s = 0;
    __syncthreads();
    for (int base = 0; base < N; base += 1024) {
        const int i = base + (int)threadIdx.x;
        const int v = (i < N) ? deg[i] : 0;
        smem[threadIdx.x] = v;
        __syncthreads();
#pragma unroll
        for (int off = 1; off < 1024; off <<= 1) {
            const int t = (threadIdx.x >= (unsigned)off) ? smem[threadIdx.x - off] : 0;
            __syncthreads();
            smem[threadIdx.x] += t;
            __syncthreads();
        }
        const int excl = smem[threadIdx.x] - v;
        const int carry = carry_s;
        if (i < N) {
            row_ptr[i] = carry + excl;
            cursor[i]  = carry + excl;
        }
        const int total = smem[1023];
        __syncthreads();
        if (threadIdx.x == 0) carry_s = carry + total;
        __syncthreads();
    }
    if (threadIdx.x == 0) row_ptr[N] = carry_s;
}

__global__ __launch_bounds__(256)
void bucket_kernel(const int* __restrict__ src, const int* __restrict__ dst,
                   int* __restrict__ cursor, int* __restrict__ esrc, int E)
{
    const int stride = gridDim.x * 256;
    for (int e = blockIdx.x * 256 + threadIdx.x; e < E; e += stride) {
        const int p = atomicAdd(&cursor[dst[e]], 1);
        esrc[p] = src[e];
    }
}

// ---------------- node-parallel segment max over bf16 rows ----------------
// m >= 0 (relu), so unsigned-short compare == float compare; 0 = identity.
__global__ __launch_bounds__(256)
void agg_max_kernel(const int* __restrict__ row_ptr, const int* __restrict__ esrc,
                    const ushort* __restrict__ m, ushort* __restrict__ agg, int N)
{
    const int wid  = (int)(((size_t)blockIdx.x * 256 + threadIdx.x) >> 6);
    const int lane = threadIdx.x & 63;
    if (wid >= N) return;
    const int beg = row_ptr[wid];
    const int end = row_ptr[wid + 1];
    ushort4 acc = make_ushort4(0, 0, 0, 0);
    int e = beg;
    for (; e + 1 < end; e += 2) {
        const int s0 = esrc[e];
        const int s1 = esrc[e + 1];
        const ushort4 v0 = *(const ushort4*)(m + (size_t)s0 * D256 + lane * 4);
        const ushort4 v1 = *(const ushort4*)(m + (size_t)s1 * D256 + lane * 4);
        acc.x = umax16(acc.x, umax16(v0.x, v1.x));
        acc.y = umax16(acc.y, umax16(v0.y, v1.y));
        acc.z = umax16(acc.z, umax16(v0.z, v1.z));
        acc.w = umax16(acc.w, umax16(v0.w, v1.w));
    }
    if (e < end) {
        const ushort4 v0 = *(const ushort4*)(m + (size_t)esrc[e] * D256 + lane * 4);
        acc.x = umax16(acc.x, v0.x);
        acc.y = umax16(acc.y, v0.y);
        acc.z = umax16(acc.z, v0.z);
        acc.w = umax16(acc.w, v0.w);
    }
    *(ushort4*)(agg + (size_t)wid * D256 + lane * 4) = acc;
}

// ------------- row-wise L2 normalize: fp32 out + bf16 copy -------------
__global__ __launch_bounds__(256)
void l2norm_kernel(const float* __restrict__ in, float* __restrict__ out_f,
                   ushort* __restrict__ out_b, int M)
{
    const int wid  = (int)(((size_t)blockIdx.x * 256 + threadIdx.x) >> 6);
    const int lane = threadIdx.x & 63;
    if (wid >= M) return;
    const float4 v = *(const float4*)(in + (size_t)wid * D256 + lane * 4);
    float ss = v.x * v.x + v.y * v.y + v.z * v.z + v.w * v.w;
#pragma unroll
    for (int o = 32; o >= 1; o >>= 1) ss += __shfl_xor(ss, o);
    const float inv = 1.0f / fmaxf(sqrtf(ss), 1e-12f);
    float4 o4;
    o4.x = v.x * inv; o4.y = v.y * inv; o4.z = v.z * inv; o4.w = v.w * inv;
    *(float4*)(out_f + (size_t)wid * D256 + lane * 4) = o4;
    ushort4 ob;
    ob.x = f2bf(o4.x); ob.y = f2bf(o4.y); ob.z = f2bf(o4.z); ob.w = f2bf(o4.w);
    *(ushort4*)(out_b + (size_t)wid * D256 + lane * 4) = ob;
}

extern "C" void kernel_launch(void* const* d_in, const int* in_sizes, int n_in,
                              void* d_out, int out_size, void* d_ws, size_t ws_size,
                              hipStream_t stream)
{
    const float* x        = (const float*)d_in[0];
    const int*   src      = (const int*)  d_in[1];
    const int*   dst      = (const int*)  d_in[2];
    const float* W_pool0  = (const float*)d_in[3];
    const float* b_pool0  = (const float*)d_in[4];
    const float* W_self0  = (const float*)d_in[5];
    const float* W_neigh0 = (const float*)d_in[6];
    const float* b0       = (const float*)d_in[7];
    const float* W_pool1  = (const float*)d_in[8];
    const float* b_pool1  = (const float*)d_in[9];
    const float* W_self1  = (const float*)d_in[10];
    const float* W_neigh1 = (const float*)d_in[11];
    const float* b1       = (const float*)d_in[12];

    const int N = in_sizes[0] / D256;
    const int E = in_sizes[1];
    const size_t NR = (size_t)N * D256;   // elems per node matrix

    float* h1  = (float*)d_out;                     // [N,256] layer-1 out (fp32)
    float* enc = (float*)d_out + NR;                // [N,256] enc_feat_input (fp32)

    // workspace layout
    ushort* xb   = (ushort*)d_ws;                   // bf16 A (x for L0, enc for L1)
    ushort* mb   = xb + NR;                         // bf16 pool msgs
    ushort* aggb = mb + NR;                         // bf16 aggregated
    float*  tmp  = (float*)(aggb + NR);             // fp32 pre-norm h0
    ushort* Bt   = (ushort*)(tmp + NR);             // 6 x [256,256] bf16 W^T
    int* row_ptr = (int*)(Bt + 6 * 256 * 256);      // N+1
    int* cursor  = row_ptr + (N + 1);
    int* deg     = cursor + N;
    int* esrc    = deg + N;                         // E

    ushort* Bt_pool0  = Bt + 0 * 65536;
    ushort* Bt_self0  = Bt + 1 * 65536;
    ushort* Bt_neigh0 = Bt + 2 * 65536;
    ushort* Bt_pool1  = Bt + 3 * 65536;
    ushort* Bt_self1  = Bt + 4 * 65536;
    ushort* Bt_neigh1 = Bt + 5 * 65536;

    const dim3 gemm_grid((N + 127) / 128, 2);
    const int  edge_blocks = (E + 255) / 256 < 2048 ? (E + 255) / 256 : 2048;
    const int  node_blocks = (N + 3) / 4;
    const int  conv_blocks = (int)((NR / 4 + 255) / 256);

    // ---------------- one-time conversions ----------------
    WP6 wp;
    wp.p[0] = { W_pool0,  Bt_pool0  };
    wp.p[1] = { W_self0,  Bt_self0  };
    wp.p[2] = { W_neigh0, Bt_neigh0 };
    wp.p[3] = { W_pool1,  Bt_pool1  };
    wp.p[4] = { W_self1,  Bt_self1  };
    wp.p[5] = { W_neigh1, Bt_neigh1 };
    wtrans_kernel<<<dim3(8, 8, 6), 256, 0, stream>>>(wp);
    f2bf_kernel<<<conv_blocks, 256, 0, stream>>>(x, xb, (int)(NR / 4));

    // ---------------- CSR build ----------------
    hipMemsetAsync(deg, 0, (size_t)N * sizeof(int), stream);
    hist_kernel<<<edge_blocks, 256, 0, stream>>>(dst, deg, E);
    scan_kernel<<<1, 1024, 0, stream>>>(deg, row_ptr, cursor, N);
    bucket_kernel<<<edge_blocks, 256, 0, stream>>>(src, dst, cursor, esrc, E);

    // ---------------- layer 0 ----------------
    mfma_gemm_kernel<0,1,1><<<gemm_grid, 256, 0, stream>>>(xb, Bt_pool0, nullptr, nullptr,
                                                           b_pool0, mb, N);
    agg_max_kernel<<<node_blocks, 256, 0, stream>>>(row_ptr, esrc, mb, aggb, N);
    mfma_gemm_kernel<1,1,0><<<gemm_grid, 256, 0, stream>>>(xb, Bt_self0, aggb, Bt_neigh0,
                                                           b0, tmp, N);
    l2norm_kernel<<<node_blocks, 256, 0, stream>>>(tmp, enc, xb, N);  // xb now holds enc bf16

    // ---------------- layer 1 ----------------
    mfma_gemm_kernel<0,1,1><<<gemm_grid, 256, 0, stream>>>(xb, Bt_pool1, nullptr, nullptr,
                                                           b_pool1, mb, N);
    agg_max_kernel<<<node_blocks, 256, 0, stream>>>(row_ptr, esrc, mb, aggb, N);
    mfma_gemm_kernel<1,0,0><<<gemm_grid, 256, 0, stream>>>(xb, Bt_self1, aggb, Bt_neigh1,
                                                           b1, h1, N);
}

// Round 4
// 429.898 us; speedup vs baseline: 5.5876x; 1.2058x over previous
//
#include <hip/hip_runtime.h>
#include <cstddef>

#define D256 256

typedef __attribute__((ext_vector_type(8))) short bf16x8;
typedef __attribute__((ext_vector_type(4))) float f32x4;

__device__ __forceinline__ ushort f2bf(float f) {
    unsigned u = __float_as_uint(f);
    return (ushort)((u + 0x7FFFu + ((u >> 16) & 1u)) >> 16);   // RNE
}
__device__ __forceinline__ ushort umax16(ushort a, ushort b) { return a > b ? a : b; }

// ---------------- MFMA GEMM: out = act( A@Bt^T (+ A2@Bt2^T) + bias ) ----------------
// A [M,256] bf16 row-major; Bt [256,256] bf16 = W^T (row n = output col, K-contiguous).
// 128x128 tile, 4 waves, 64x64 per wave, BK=32, 16x16x32 MFMA.
// LDS rows padded to 40 ushorts (80B) -> conflict-free ds_read_b128 at row-stride access.
template<int DUAL, int RELU, int OUT_BF16>
__global__ __launch_bounds__(256)
void mfma_gemm_kernel(const ushort* __restrict__ A, const ushort* __restrict__ Bt,
                      const ushort* __restrict__ A2, const ushort* __restrict__ Bt2,
                      const float* __restrict__ bias, void* __restrict__ outp, int M)
{
    __shared__ ushort As[128 * 40];
    __shared__ ushort Bs[128 * 40];
    const int t    = threadIdx.x;
    const int m0   = blockIdx.x * 128;
    const int n0   = blockIdx.y * 128;
    const int lane = t & 63;
    const int wave = t >> 6;
    const int wr   = (wave >> 1) * 64;   // wave's row base within tile
    const int wc   = (wave & 1) * 64;    // wave's col base within tile
    const int lr   = lane & 15;
    const int kg   = lane >> 4;          // k-group 0..3
    const int srow = t >> 2;             // staging row 0..63
    const int sch  = t & 3;              // staging 16B chunk 0..3

    f32x4 acc[4][4];
#pragma unroll
    for (int i = 0; i < 4; ++i)
#pragma unroll
        for (int j = 0; j < 4; ++j) acc[i][j] = (f32x4)(0.0f);

    const int npass = DUAL ? 2 : 1;
    for (int pass = 0; pass < npass; ++pass) {
        const ushort* __restrict__ Ap = (DUAL && pass) ? A2 : A;
        const ushort* __restrict__ Bp = (DUAL && pass) ? Bt2 : Bt;
        for (int k0 = 0; k0 < D256; k0 += 32) {
            __syncthreads();
#pragma unroll
            for (int rep = 0; rep < 2; ++rep) {
                const int row  = rep * 64 + srow;
                const int grow = m0 + row;
                uint4 av = make_uint4(0, 0, 0, 0);
                if (grow < M)
                    av = *(const uint4*)(Ap + (size_t)grow * D256 + k0 + sch * 8);
                *(uint4*)&As[row * 40 + sch * 8] = av;
                const uint4 bv = *(const uint4*)(Bp + (size_t)(n0 + row) * D256 + k0 + sch * 8);
                *(uint4*)&Bs[row * 40 + sch * 8] = bv;
            }
            __syncthreads();
            bf16x8 af[4], bfr[4];
#pragma unroll
            for (int mi = 0; mi < 4; ++mi)
                af[mi] = *(const bf16x8*)&As[(wr + mi * 16 + lr) * 40 + kg * 8];
#pragma unroll
            for (int ni = 0; ni < 4; ++ni)
                bfr[ni] = *(const bf16x8*)&Bs[(wc + ni * 16 + lr) * 40 + kg * 8];
#pragma unroll
            for (int mi = 0; mi < 4; ++mi)
#pragma unroll
                for (int ni = 0; ni < 4; ++ni)
                    acc[mi][ni] = __builtin_amdgcn_mfma_f32_16x16x32_bf16(
                        af[mi], bfr[ni], acc[mi][ni], 0, 0, 0);
        }
    }

    // C/D layout: col = lane&15, row = (lane>>4)*4 + j
#pragma unroll
    for (int ni = 0; ni < 4; ++ni) {
        const int col = n0 + wc + ni * 16 + lr;
        const float bb = bias[col];
#pragma unroll
        for (int mi = 0; mi < 4; ++mi) {
            const int rbase = m0 + wr + mi * 16 + kg * 4;
#pragma unroll
            for (int j = 0; j < 4; ++j) {
                const int row = rbase + j;
                if (row < M) {
                    float v = acc[mi][ni][j] + bb;
                    if (RELU) v = fmaxf(v, 0.0f);
                    if (OUT_BF16)
                        ((ushort*)outp)[(size_t)row * D256 + col] = f2bf(v);
                    else
                        ((float*)outp)[(size_t)row * D256 + col] = v;
                }
            }
        }
    }
}

// ---------------- fp32 -> bf16 convert ----------------
__global__ __launch_bounds__(256)
void f2bf_kernel(const float* __restrict__ in, ushort* __restrict__ out, int n4)
{
    const int i = blockIdx.x * 256 + threadIdx.x;
    if (i >= n4) return;
    const float4 v = ((const float4*)in)[i];
    ushort4 o;
    o.x = f2bf(v.x); o.y = f2bf(v.y); o.z = f2bf(v.z); o.w = f2bf(v.w);
    ((ushort4*)out)[i] = o;
}

// ---------------- weight transpose+convert: Bt[n][k] = bf16(W[k][n]) ----------------
struct WP  { const float* w; ushort* o; };
struct WP6 { WP p[6]; };
__global__ __launch_bounds__(256)
void wtrans_kernel(WP6 ps)
{
    const float* __restrict__ W = ps.p[blockIdx.z].w;
    ushort* __restrict__ O      = ps.p[blockIdx.z].o;
    __shared__ float sm[32][33];
    const int tx = threadIdx.x & 31, ty = threadIdx.x >> 5;
    const int k0 = blockIdx.x * 32, n0 = blockIdx.y * 32;
#pragma unroll
    for (int i = 0; i < 4; ++i)
        sm[ty + i * 8][tx] = W[(size_t)(k0 + ty + i * 8) * D256 + n0 + tx];
    __syncthreads();
#pragma unroll
    for (int i = 0; i < 4; ++i)
        O[(size_t)(n0 + ty + i * 8) * D256 + k0 + tx] = f2bf(sm[tx][ty + i * 8]);
}

// ---------------- CSR build: histogram -> hierarchical scan -> bucket scatter ----------------
__global__ __launch_bounds__(256)
void hist_kernel(const int* __restrict__ dst, int* __restrict__ deg, int E)
{
    const int stride = gridDim.x * 256;
    for (int e = blockIdx.x * 256 + threadIdx.x; e < E; e += stride)
        atomicAdd(&deg[dst[e]], 1);
}

// per-block (1024 elems) inclusive scan: wave shfl scan + 16-wave LDS combine
__global__ __launch_bounds__(1024)
void blockscan_kernel(const int* __restrict__ deg, int* __restrict__ incl,
                      int* __restrict__ partials, int N)
{
    __shared__ int wt[16];
    const int i    = blockIdx.x * 1024 + threadIdx.x;
    const int lane = threadIdx.x & 63;
    const int wv   = threadIdx.x >> 6;
    const int v    = (i < N) ? deg[i] : 0;
    int s = v;
#pragma unroll
    for (int o = 1; o < 64; o <<= 1) {
        const int t = __shfl_up(s, o);
        if (lane >= o) s += t;
    }
    if (lane == 63) wt[wv] = s;
    __syncthreads();
    if (wv == 0 && lane < 16) {
        const int w = wt[lane];
        int ws = w;
#pragma unroll
        for (int o = 1; o < 16; o <<= 1) {
            const int t = __shfl_up(ws, o);
            if (lane >= o) ws += t;
        }
        wt[lane] = ws - w;   // exclusive wave offset
    }
    __syncthreads();
    s += wt[wv];
    if (i < N) incl[i] = s;
    if (threadIdx.x == 1023) partials[blockIdx.x] = s;
}

// scan the (<=1024) block totals into exclusive offsets; single block
__global__ __launch_bounds__(1024)
void scanp_kernel(int* __restrict__ partials, int nb)
{
    __shared__ int sm[1024];
    const int v = (threadIdx.x < (unsigned)nb) ? partials[threadIdx.x] : 0;
    sm[threadIdx.x] = v;
    __syncthreads();
#pragma unroll
    for (int off = 1; off < 1024; off <<= 1) {
        const int t = (threadIdx.x >= (unsigned)off) ? sm[threadIdx.x - off] : 0;
        __syncthreads();
        sm[threadIdx.x] += t;
        __syncthreads();
    }
    if (threadIdx.x < (unsigned)nb) partials[threadIdx.x] = sm[threadIdx.x] - v;
}

__global__ __launch_bounds__(1024)
void finalize_kernel(const int* __restrict__ deg, const int* __restrict__ incl,
                     const int* __restrict__ partials, int* __restrict__ row_ptr,
                     int* __restrict__ cursor, int N, int E)
{
    const int i = blockIdx.x * 1024 + threadIdx.x;
    if (i < N) {
        const int ex = partials[blockIdx.x] + incl[i] - deg[i];
        row_ptr[i] = ex;
        cursor[i]  = ex;
    }
    if (i == 0) row_ptr[N] = E;
}

__global__ __launch_bounds__(256)
void bucket_kernel(const int* __restrict__ src, const int* __restrict__ dst,
                   int* __restrict__ cursor, int* __restrict__ esrc, int E)
{
    const int stride = gridDim.x * 256;
    for (int e = blockIdx.x * 256 + threadIdx.x; e < E; e += stride) {
        const int p = atomicAdd(&cursor[dst[e]], 1);
        esrc[p] = src[e];
    }
}

// ---------------- node-parallel segment max over bf16 rows ----------------
// m >= 0 (relu), so unsigned-short compare == float compare; 0 = identity.
__global__ __launch_bounds__(256)
void agg_max_kernel(const int* __restrict__ row_ptr, const int* __restrict__ esrc,
                    const ushort* __restrict__ m, ushort* __restrict__ agg, int N)
{
    const int wid  = (int)(((size_t)blockIdx.x * 256 + threadIdx.x) >> 6);
    const int lane = threadIdx.x & 63;
    if (wid >= N) return;
    const int beg = row_ptr[wid];
    const int end = row_ptr[wid + 1];
    ushort4 acc = make_ushort4(0, 0, 0, 0);
    int e = beg;
    for (; e + 1 < end; e += 2) {
        const int s0 = esrc[e];
        const int s1 = esrc[e + 1];
        const ushort4 v0 = *(const ushort4*)(m + (size_t)s0 * D256 + lane * 4);
        const ushort4 v1 = *(const ushort4*)(m + (size_t)s1 * D256 + lane * 4);
        acc.x = umax16(acc.x, umax16(v0.x, v1.x));
        acc.y = umax16(acc.y, umax16(v0.y, v1.y));
        acc.z = umax16(acc.z, umax16(v0.z, v1.z));
        acc.w = umax16(acc.w, umax16(v0.w, v1.w));
    }
    if (e < end) {
        const ushort4 v0 = *(const ushort4*)(m + (size_t)esrc[e] * D256 + lane * 4);
        acc.x = umax16(acc.x, v0.x);
        acc.y = umax16(acc.y, v0.y);
        acc.z = umax16(acc.z, v0.z);
        acc.w = umax16(acc.w, v0.w);
    }
    *(ushort4*)(agg + (size_t)wid * D256 + lane * 4) = acc;
}

// ------------- row-wise L2 normalize: fp32 out + bf16 copy -------------
__global__ __launch_bounds__(256)
void l2norm_kernel(const float* __restrict__ in, float* __restrict__ out_f,
                   ushort* __restrict__ out_b, int M)
{
    const int wid  = (int)(((size_t)blockIdx.x * 256 + threadIdx.x) >> 6);
    const int lane = threadIdx.x & 63;
    if (wid >= M) return;
    const float4 v = *(const float4*)(in + (size_t)wid * D256 + lane * 4);
    float ss = v.x * v.x + v.y * v.y + v.z * v.z + v.w * v.w;
#pragma unroll
    for (int o = 32; o >= 1; o >>= 1) ss += __shfl_xor(ss, o);
    const float inv = 1.0f / fmaxf(sqrtf(ss), 1e-12f);
    float4 o4;
    o4.x = v.x * inv; o4.y = v.y * inv; o4.z = v.z * inv; o4.w = v.w * inv;
    *(float4*)(out_f + (size_t)wid * D256 + lane * 4) = o4;
    ushort4 ob;
    ob.x = f2bf(o4.x); ob.y = f2bf(o4.y); ob.z = f2bf(o4.z); ob.w = f2bf(o4.w);
    *(ushort4*)(out_b + (size_t)wid * D256 + lane * 4) = ob;
}

extern "C" void kernel_launch(void* const* d_in, const int* in_sizes, int n_in,
                              void* d_out, int out_size, void* d_ws, size_t ws_size,
                              hipStream_t stream)
{
    const float* x        = (const float*)d_in[0];
    const int*   src      = (const int*)  d_in[1];
    const int*   dst      = (const int*)  d_in[2];
    const float* W_pool0  = (const float*)d_in[3];
    const float* b_pool0  = (const float*)d_in[4];
    const float* W_self0  = (const float*)d_in[5];
    const float* W_neigh0 = (const float*)d_in[6];
    const float* b0       = (const float*)d_in[7];
    const float* W_pool1  = (const float*)d_in[8];
    const float* b_pool1  = (const float*)d_in[9];
    const float* W_self1  = (const float*)d_in[10];
    const float* W_neigh1 = (const float*)d_in[11];
    const float* b1       = (const float*)d_in[12];

    const int N = in_sizes[0] / D256;
    const int E = in_sizes[1];
    const size_t NR = (size_t)N * D256;   // elems per node matrix

    float* h1  = (float*)d_out;                     // [N,256] layer-1 out (fp32)
    float* enc = (float*)d_out + NR;                // [N,256] enc_feat_input (fp32)

    // workspace layout
    ushort* xb   = (ushort*)d_ws;                   // bf16 A (x for L0, enc for L1)
    ushort* mb   = xb + NR;                         // bf16 pool msgs
    ushort* aggb = mb + NR;                         // bf16 aggregated
    float*  tmp  = (float*)(aggb + NR);             // fp32 pre-norm h0
    ushort* Bt   = (ushort*)(tmp + NR);             // 6 x [256,256] bf16 W^T
    int* row_ptr = (int*)(Bt + 6 * 256 * 256);      // N+1
    int* cursor  = row_ptr + (N + 1);
    int* deg     = cursor + N;
    int* incl    = deg + N;                         // N (inclusive scan scratch)
    int* partials= incl + N;                        // <=1024
    int* esrc    = partials + 1024;                 // E

    ushort* Bt_pool0  = Bt + 0 * 65536;
    ushort* Bt_self0  = Bt + 1 * 65536;
    ushort* Bt_neigh0 = Bt + 2 * 65536;
    ushort* Bt_pool1  = Bt + 3 * 65536;
    ushort* Bt_self1  = Bt + 4 * 65536;
    ushort* Bt_neigh1 = Bt + 5 * 65536;

    const dim3 gemm_grid((N + 127) / 128, 2);
    const int  edge_blocks = (E + 255) / 256 < 2048 ? (E + 255) / 256 : 2048;
    const int  node_blocks = (N + 3) / 4;
    const int  conv_blocks = (int)((NR / 4 + 255) / 256);
    const int  scan_blocks = (N + 1023) / 1024;

    // ---------------- one-time conversions ----------------
    WP6 wp;
    wp.p[0] = { W_pool0,  Bt_pool0  };
    wp.p[1] = { W_self0,  Bt_self0  };
    wp.p[2] = { W_neigh0, Bt_neigh0 };
    wp.p[3] = { W_pool1,  Bt_pool1  };
    wp.p[4] = { W_self1,  Bt_self1  };
    wp.p[5] = { W_neigh1, Bt_neigh1 };
    wtrans_kernel<<<dim3(8, 8, 6), 256, 0, stream>>>(wp);
    f2bf_kernel<<<conv_blocks, 256, 0, stream>>>(x, xb, (int)(NR / 4));

    // ---------------- CSR build ----------------
    hipMemsetAsync(deg, 0, (size_t)N * sizeof(int), stream);
    hist_kernel<<<edge_blocks, 256, 0, stream>>>(dst, deg, E);
    blockscan_kernel<<<scan_blocks, 1024, 0, stream>>>(deg, incl, partials, N);
    scanp_kernel<<<1, 1024, 0, stream>>>(partials, scan_blocks);
    finalize_kernel<<<scan_blocks, 1024, 0, stream>>>(deg, incl, partials,
                                                      row_ptr, cursor, N, E);
    bucket_kernel<<<edge_blocks, 256, 0, stream>>>(src, dst, cursor, esrc, E);

    // ---------------- layer 0 ----------------
    mfma_gemm_kernel<0,1,1><<<gemm_grid, 256, 0, stream>>>(xb, Bt_pool0, nullptr, nullptr,
                                                           b_pool0, mb, N);
    agg_max_kernel<<<node_blocks, 256, 0, stream>>>(row_ptr, esrc, mb, aggb, N);
    mfma_gemm_kernel<1,1,0><<<gemm_grid, 256, 0, stream>>>(xb, Bt_self0, aggb, Bt_neigh0,
                                                           b0, tmp, N);
    l2norm_kernel<<<node_blocks, 256, 0, stream>>>(tmp, enc, xb, N);  // xb now holds enc bf16

    // ---------------- layer 1 ----------------
    mfma_gemm_kernel<0,1,1><<<gemm_grid, 256, 0, stream>>>(xb, Bt_pool1, nullptr, nullptr,
                                                           b_pool1, mb, N);
    agg_max_kernel<<<node_blocks, 256, 0, stream>>>(row_ptr, esrc, mb, aggb, N);
    mfma_gemm_kernel<1,0,0><<<gemm_grid, 256, 0, stream>>>(xb, Bt_self1, aggb, Bt_neigh1,
                                                           b1, h1, N);
}

// Round 5
// 426.023 us; speedup vs baseline: 5.6385x; 1.0091x over previous
//
#include <hip/hip_runtime.h>
#include <cstddef>

#define D256 256

typedef __attribute__((ext_vector_type(8))) short bf16x8;
typedef __attribute__((ext_vector_type(4))) float f32x4;

__device__ __forceinline__ ushort f2bf(float f) {
    unsigned u = __float_as_uint(f);
    return (ushort)((u + 0x7FFFu + ((u >> 16) & 1u)) >> 16);   // RNE
}
__device__ __forceinline__ ushort umax16(ushort a, ushort b) { return a > b ? a : b; }
__device__ __forceinline__ ushort4 vmax4(ushort4 a, ushort4 b) {
    return make_ushort4(umax16(a.x, b.x), umax16(a.y, b.y),
                        umax16(a.z, b.z), umax16(a.w, b.w));
}

// ---------------- MFMA GEMM: out = act( A@Bt^T (+ A2@Bt2^T) + bias ) ----------------
// A [M,256] bf16 row-major; Bt [256,256] bf16 = W^T (row n = output col, K-contiguous).
// 128x128 tile, 4 waves, 64x64 per wave, BK=32, 16x16x32 MFMA.
// LDS rows padded to 40 ushorts (80B) -> conflict-free ds_read_b128 at row-stride access.
template<int DUAL, int RELU, int OUT_BF16>
__global__ __launch_bounds__(256)
void mfma_gemm_kernel(const ushort* __restrict__ A, const ushort* __restrict__ Bt,
                      const ushort* __restrict__ A2, const ushort* __restrict__ Bt2,
                      const float* __restrict__ bias, void* __restrict__ outp, int M)
{
    __shared__ ushort As[128 * 40];
    __shared__ ushort Bs[128 * 40];
    const int t    = threadIdx.x;
    const int m0   = blockIdx.x * 128;
    const int n0   = blockIdx.y * 128;
    const int lane = t & 63;
    const int wave = t >> 6;
    const int wr   = (wave >> 1) * 64;   // wave's row base within tile
    const int wc   = (wave & 1) * 64;    // wave's col base within tile
    const int lr   = lane & 15;
    const int kg   = lane >> 4;          // k-group 0..3
    const int srow = t >> 2;             // staging row 0..63
    const int sch  = t & 3;              // staging 16B chunk 0..3

    f32x4 acc[4][4];
#pragma unroll
    for (int i = 0; i < 4; ++i)
#pragma unroll
        for (int j = 0; j < 4; ++j) acc[i][j] = (f32x4)(0.0f);

    const int npass = DUAL ? 2 : 1;
    for (int pass = 0; pass < npass; ++pass) {
        const ushort* __restrict__ Ap = (DUAL && pass) ? A2 : A;
        const ushort* __restrict__ Bp = (DUAL && pass) ? Bt2 : Bt;
        for (int k0 = 0; k0 < D256; k0 += 32) {
            __syncthreads();
#pragma unroll
            for (int rep = 0; rep < 2; ++rep) {
                const int row  = rep * 64 + srow;
                const int grow = m0 + row;
                uint4 av = make_uint4(0, 0, 0, 0);
                if (grow < M)
                    av = *(const uint4*)(Ap + (size_t)grow * D256 + k0 + sch * 8);
                *(uint4*)&As[row * 40 + sch * 8] = av;
                const uint4 bv = *(const uint4*)(Bp + (size_t)(n0 + row) * D256 + k0 + sch * 8);
                *(uint4*)&Bs[row * 40 + sch * 8] = bv;
            }
            __syncthreads();
            bf16x8 af[4], bfr[4];
#pragma unroll
            for (int mi = 0; mi < 4; ++mi)
                af[mi] = *(const bf16x8*)&As[(wr + mi * 16 + lr) * 40 + kg * 8];
#pragma unroll
            for (int ni = 0; ni < 4; ++ni)
                bfr[ni] = *(const bf16x8*)&Bs[(wc + ni * 16 + lr) * 40 + kg * 8];
#pragma unroll
            for (int mi = 0; mi < 4; ++mi)
#pragma unroll
                for (int ni = 0; ni < 4; ++ni)
                    acc[mi][ni] = __builtin_amdgcn_mfma_f32_16x16x32_bf16(
                        af[mi], bfr[ni], acc[mi][ni], 0, 0, 0);
        }
    }

    // C/D layout: col = lane&15, row = (lane>>4)*4 + j
#pragma unroll
    for (int ni = 0; ni < 4; ++ni) {
        const int col = n0 + wc + ni * 16 + lr;
        const float bb = bias[col];
#pragma unroll
        for (int mi = 0; mi < 4; ++mi) {
            const int rbase = m0 + wr + mi * 16 + kg * 4;
#pragma unroll
            for (int j = 0; j < 4; ++j) {
                const int row = rbase + j;
                if (row < M) {
                    float v = acc[mi][ni][j] + bb;
                    if (RELU) v = fmaxf(v, 0.0f);
                    if (OUT_BF16)
                        ((ushort*)outp)[(size_t)row * D256 + col] = f2bf(v);
                    else
                        ((float*)outp)[(size_t)row * D256 + col] = v;
                }
            }
        }
    }
}

// ---------------- fp32 -> bf16 convert ----------------
__global__ __launch_bounds__(256)
void f2bf_kernel(const float* __restrict__ in, ushort* __restrict__ out, int n4)
{
    const int i = blockIdx.x * 256 + threadIdx.x;
    if (i >= n4) return;
    const float4 v = ((const float4*)in)[i];
    ushort4 o;
    o.x = f2bf(v.x); o.y = f2bf(v.y); o.z = f2bf(v.z); o.w = f2bf(v.w);
    ((ushort4*)out)[i] = o;
}

// ---------------- weight transpose+convert: Bt[n][k] = bf16(W[k][n]) ----------------
struct WP  { const float* w; ushort* o; };
struct WP6 { WP p[6]; };
__global__ __launch_bounds__(256)
void wtrans_kernel(WP6 ps)
{
    const float* __restrict__ W = ps.p[blockIdx.z].w;
    ushort* __restrict__ O      = ps.p[blockIdx.z].o;
    __shared__ float sm[32][33];
    const int tx = threadIdx.x & 31, ty = threadIdx.x >> 5;
    const int k0 = blockIdx.x * 32, n0 = blockIdx.y * 32;
#pragma unroll
    for (int i = 0; i < 4; ++i)
        sm[ty + i * 8][tx] = W[(size_t)(k0 + ty + i * 8) * D256 + n0 + tx];
    __syncthreads();
#pragma unroll
    for (int i = 0; i < 4; ++i)
        O[(size_t)(n0 + ty + i * 8) * D256 + k0 + tx] = f2bf(sm[tx][ty + i * 8]);
}

// ---------------- CSR build: histogram -> hierarchical scan -> bucket scatter ----------------
__global__ __launch_bounds__(256)
void hist_kernel(const int* __restrict__ dst, int* __restrict__ deg, int E)
{
    const int stride = gridDim.x * 256;
    for (int e = blockIdx.x * 256 + threadIdx.x; e < E; e += stride)
        atomicAdd(&deg[dst[e]], 1);
}

// per-block (1024 elems) inclusive scan: wave shfl scan + 16-wave LDS combine
__global__ __launch_bounds__(1024)
void blockscan_kernel(const int* __restrict__ deg, int* __restrict__ incl,
                      int* __restrict__ partials, int N)
{
    __shared__ int wt[16];
    const int i    = blockIdx.x * 1024 + threadIdx.x;
    const int lane = threadIdx.x & 63;
    const int wv   = threadIdx.x >> 6;
    const int v    = (i < N) ? deg[i] : 0;
    int s = v;
#pragma unroll
    for (int o = 1; o < 64; o <<= 1) {
        const int t = __shfl_up(s, o);
        if (lane >= o) s += t;
    }
    if (lane == 63) wt[wv] = s;
    __syncthreads();
    if (wv == 0 && lane < 16) {
        const int w = wt[lane];
        int ws = w;
#pragma unroll
        for (int o = 1; o < 16; o <<= 1) {
            const int t = __shfl_up(ws, o);
            if (lane >= o) ws += t;
        }
        wt[lane] = ws - w;   // exclusive wave offset
    }
    __syncthreads();
    s += wt[wv];
    if (i < N) incl[i] = s;
    if (threadIdx.x == 1023) partials[blockIdx.x] = s;
}

// scan the (<=1024) block totals into exclusive offsets; single block
__global__ __launch_bounds__(1024)
void scanp_kernel(int* __restrict__ partials, int nb)
{
    __shared__ int sm[1024];
    const int v = (threadIdx.x < (unsigned)nb) ? partials[threadIdx.x] : 0;
    sm[threadIdx.x] = v;
    __syncthreads();
#pragma unroll
    for (int off = 1; off < 1024; off <<= 1) {
        const int t = (threadIdx.x >= (unsigned)off) ? sm[threadIdx.x - off] : 0;
        __syncthreads();
        sm[threadIdx.x] += t;
        __syncthreads();
    }
    if (threadIdx.x < (unsigned)nb) partials[threadIdx.x] = sm[threadIdx.x] - v;
}

__global__ __launch_bounds__(1024)
void finalize_kernel(const int* __restrict__ deg, const int* __restrict__ incl,
                     const int* __restrict__ partials, int* __restrict__ row_ptr,
                     int* __restrict__ cursor, int N, int E)
{
    const int i = blockIdx.x * 1024 + threadIdx.x;
    if (i < N) {
        const int ex = partials[blockIdx.x] + incl[i] - deg[i];
        row_ptr[i] = ex;
        cursor[i]  = ex;
    }
    if (i == 0) row_ptr[N] = E;
}

__global__ __launch_bounds__(256)
void bucket_kernel(const int* __restrict__ src, const int* __restrict__ dst,
                   int* __restrict__ cursor, int* __restrict__ esrc, int E)
{
    const int stride = gridDim.x * 256;
    for (int e = blockIdx.x * 256 + threadIdx.x; e < E; e += stride) {
        const int p = atomicAdd(&cursor[dst[e]], 1);
        esrc[p] = src[e];
    }
}

// ---------------- node-parallel segment max over bf16 rows ----------------
// m >= 0 (relu), so unsigned-short compare == float compare; 0 = identity.
// 8-deep batched loads: issue all 8 row loads before consuming (MLP, not chain).
__global__ __launch_bounds__(256)
void agg_max_kernel(const int* __restrict__ row_ptr, const int* __restrict__ esrc,
                    const ushort* __restrict__ m, ushort* __restrict__ agg, int N)
{
    const int wid  = (int)(((size_t)blockIdx.x * 256 + threadIdx.x) >> 6);
    const int lane = threadIdx.x & 63;
    if (wid >= N) return;
    const int beg = row_ptr[wid];
    const int end = row_ptr[wid + 1];
    const size_t off = (size_t)(lane * 4);

    ushort4 a0 = make_ushort4(0, 0, 0, 0);
    ushort4 a1 = a0, a2 = a0, a3 = a0;
    int e = beg;
    for (; e + 8 <= end; e += 8) {
        int s[8];
#pragma unroll
        for (int q = 0; q < 8; ++q) s[q] = esrc[e + q];
        ushort4 v[8];
#pragma unroll
        for (int q = 0; q < 8; ++q)
            v[q] = *(const ushort4*)(m + (size_t)s[q] * D256 + off);
        a0 = vmax4(a0, vmax4(v[0], v[4]));
        a1 = vmax4(a1, vmax4(v[1], v[5]));
        a2 = vmax4(a2, vmax4(v[2], v[6]));
        a3 = vmax4(a3, vmax4(v[3], v[7]));
    }
    for (; e + 2 <= end; e += 2) {
        const int s0 = esrc[e];
        const int s1 = esrc[e + 1];
        const ushort4 v0 = *(const ushort4*)(m + (size_t)s0 * D256 + off);
        const ushort4 v1 = *(const ushort4*)(m + (size_t)s1 * D256 + off);
        a0 = vmax4(a0, v0);
        a1 = vmax4(a1, v1);
    }
    if (e < end) {
        const ushort4 v0 = *(const ushort4*)(m + (size_t)esrc[e] * D256 + off);
        a2 = vmax4(a2, v0);
    }
    const ushort4 r = vmax4(vmax4(a0, a1), vmax4(a2, a3));
    *(ushort4*)(agg + (size_t)wid * D256 + off) = r;
}

// ------------- row-wise L2 normalize: fp32 out + bf16 copy -------------
__global__ __launch_bounds__(256)
void l2norm_kernel(const float* __restrict__ in, float* __restrict__ out_f,
                   ushort* __restrict__ out_b, int M)
{
    const int wid  = (int)(((size_t)blockIdx.x * 256 + threadIdx.x) >> 6);
    const int lane = threadIdx.x & 63;
    if (wid >= M) return;
    const float4 v = *(const float4*)(in + (size_t)wid * D256 + lane * 4);
    float ss = v.x * v.x + v.y * v.y + v.z * v.z + v.w * v.w;
#pragma unroll
    for (int o = 32; o >= 1; o >>= 1) ss += __shfl_xor(ss, o);
    const float inv = 1.0f / fmaxf(sqrtf(ss), 1e-12f);
    float4 o4;
    o4.x = v.x * inv; o4.y = v.y * inv; o4.z = v.z * inv; o4.w = v.w * inv;
    *(float4*)(out_f + (size_t)wid * D256 + lane * 4) = o4;
    ushort4 ob;
    ob.x = f2bf(o4.x); ob.y = f2bf(o4.y); ob.z = f2bf(o4.z); ob.w = f2bf(o4.w);
    *(ushort4*)(out_b + (size_t)wid * D256 + lane * 4) = ob;
}

extern "C" void kernel_launch(void* const* d_in, const int* in_sizes, int n_in,
                              void* d_out, int out_size, void* d_ws, size_t ws_size,
                              hipStream_t stream)
{
    const float* x        = (const float*)d_in[0];
    const int*   src      = (const int*)  d_in[1];
    const int*   dst      = (const int*)  d_in[2];
    const float* W_pool0  = (const float*)d_in[3];
    const float* b_pool0  = (const float*)d_in[4];
    const float* W_self0  = (const float*)d_in[5];
    const float* W_neigh0 = (const float*)d_in[6];
    const float* b0       = (const float*)d_in[7];
    const float* W_pool1  = (const float*)d_in[8];
    const float* b_pool1  = (const float*)d_in[9];
    const float* W_self1  = (const float*)d_in[10];
    const float* W_neigh1 = (const float*)d_in[11];
    const float* b1       = (const float*)d_in[12];

    const int N = in_sizes[0] / D256;
    const int E = in_sizes[1];
    const size_t NR = (size_t)N * D256;   // elems per node matrix

    float* h1  = (float*)d_out;                     // [N,256] layer-1 out (fp32)
    float* enc = (float*)d_out + NR;                // [N,256] enc_feat_input (fp32)

    // workspace layout
    ushort* xb   = (ushort*)d_ws;                   // bf16 A (x for L0, enc for L1)
    ushort* mb   = xb + NR;                         // bf16 pool msgs
    ushort* aggb = mb + NR;                         // bf16 aggregated
    float*  tmp  = (float*)(aggb + NR);             // fp32 pre-norm h0
    ushort* Bt   = (ushort*)(tmp + NR);             // 6 x [256,256] bf16 W^T
    int* row_ptr = (int*)(Bt + 6 * 256 * 256);      // N+1
    int* cursor  = row_ptr + (N + 1);
    int* deg     = cursor + N;
    int* incl    = deg + N;                         // N (inclusive scan scratch)
    int* partials= incl + N;                        // <=1024
    int* esrc    = partials + 1024;                 // E

    ushort* Bt_pool0  = Bt + 0 * 65536;
    ushort* Bt_self0  = Bt + 1 * 65536;
    ushort* Bt_neigh0 = Bt + 2 * 65536;
    ushort* Bt_pool1  = Bt + 3 * 65536;
    ushort* Bt_self1  = Bt + 4 * 65536;
    ushort* Bt_neigh1 = Bt + 5 * 65536;

    const dim3 gemm_grid((N + 127) / 128, 2);
    const int  edge_blocks = (E + 255) / 256 < 2048 ? (E + 255) / 256 : 2048;
    const int  node_blocks = (N + 3) / 4;
    const int  conv_blocks = (int)((NR / 4 + 255) / 256);
    const int  scan_blocks = (N + 1023) / 1024;

    // ---------------- one-time conversions ----------------
    WP6 wp;
    wp.p[0] = { W_pool0,  Bt_pool0  };
    wp.p[1] = { W_self0,  Bt_self0  };
    wp.p[2] = { W_neigh0, Bt_neigh0 };
    wp.p[3] = { W_pool1,  Bt_pool1  };
    wp.p[4] = { W_self1,  Bt_self1  };
    wp.p[5] = { W_neigh1, Bt_neigh1 };
    wtrans_kernel<<<dim3(8, 8, 6), 256, 0, stream>>>(wp);
    f2bf_kernel<<<conv_blocks, 256, 0, stream>>>(x, xb, (int)(NR / 4));

    // ---------------- CSR build ----------------
    hipMemsetAsync(deg, 0, (size_t)N * sizeof(int), stream);
    hist_kernel<<<edge_blocks, 256, 0, stream>>>(dst, deg, E);
    blockscan_kernel<<<scan_blocks, 1024, 0, stream>>>(deg, incl, partials, N);
    scanp_kernel<<<1, 1024, 0, stream>>>(partials, scan_blocks);
    finalize_kernel<<<scan_blocks, 1024, 0, stream>>>(deg, incl, partials,
                                                      row_ptr, cursor, N, E);
    bucket_kernel<<<edge_blocks, 256, 0, stream>>>(src, dst, cursor, esrc, E);

    // ---------------- layer 0 ----------------
    mfma_gemm_kernel<0,1,1><<<gemm_grid, 256, 0, stream>>>(xb, Bt_pool0, nullptr, nullptr,
                                                           b_pool0, mb, N);
    agg_max_kernel<<<node_blocks, 256, 0, stream>>>(row_ptr, esrc, mb, aggb, N);
    mfma_gemm_kernel<1,1,0><<<gemm_grid, 256, 0, stream>>>(xb, Bt_self0, aggb, Bt_neigh0,
                                                           b0, tmp, N);
    l2norm_kernel<<<node_blocks, 256, 0, stream>>>(tmp, enc, xb, N);  // xb now holds enc bf16

    // ---------------- layer 1 ----------------
    mfma_gemm_kernel<0,1,1><<<gemm_grid, 256, 0, stream>>>(xb, Bt_pool1, nullptr, nullptr,
                                                           b_pool1, mb, N);
    agg_max_kernel<<<node_blocks, 256, 0, stream>>>(row_ptr, esrc, mb, aggb, N);
    mfma_gemm_kernel<1,0,0><<<gemm_grid, 256, 0, stream>>>(xb, Bt_self1, aggb, Bt_neigh1,
                                                           b1, h1, N);
}

// Round 6
// 386.237 us; speedup vs baseline: 6.2193x; 1.1030x over previous
//
#include <hip/hip_runtime.h>
#include <cstddef>

#define D256 256

typedef __attribute__((ext_vector_type(8))) short bf16x8;
typedef __attribute__((ext_vector_type(4))) float f32x4;

// global -> LDS direct (16B per lane, wave-uniform LDS base + lane*16)
#define GLOAD16(gptr, lptr)                                                         \
    __builtin_amdgcn_global_load_lds(                                               \
        (const __attribute__((address_space(1))) unsigned int*)(gptr),              \
        (__attribute__((address_space(3))) unsigned int*)(lptr), 16, 0, 0)

__device__ __forceinline__ ushort f2bf(float f) {
    unsigned u = __float_as_uint(f);
    return (ushort)((u + 0x7FFFu + ((u >> 16) & 1u)) >> 16);   // RNE
}
__device__ __forceinline__ ushort umax16(ushort a, ushort b) { return a > b ? a : b; }
__device__ __forceinline__ ushort4 vmax4(ushort4 a, ushort4 b) {
    return make_ushort4(umax16(a.x, b.x), umax16(a.y, b.y),
                        umax16(a.z, b.z), umax16(a.w, b.w));
}

// ---------------- MFMA GEMM: out = act( A@Bt^T (+ A2@Bt2^T) + bias ) ----------------
// A [M,256] bf16 row-major; Bt [256,256] bf16 = W^T (row n = output col, K-contiguous).
// 128x128 tile, 4 waves (2x2), 64x64/wave, BK=32, 16x16x32 MFMA.
// Staging via global_load_lds dwordx4 into LINEAR LDS [row][32]; fragment
// ds_read_b128 at 64B row-stride = 2 lanes/bank = conflict-free (m136).
template<int DUAL, int RELU, int OUT_BF16>
__global__ __launch_bounds__(256)
void mfma_gemm_kernel(const ushort* __restrict__ A, const ushort* __restrict__ Bt,
                      const ushort* __restrict__ A2, const ushort* __restrict__ Bt2,
                      const float* __restrict__ bias, void* __restrict__ outp, int M)
{
    __shared__ ushort smem[(DUAL ? 4 : 2) * 128 * 32];
    ushort* const As  = smem;
    ushort* const Bs  = smem + 4096;
    ushort* const A2s = smem + (DUAL ? 8192 : 0);
    ushort* const B2s = smem + (DUAL ? 12288 : 0);

    const int t    = threadIdx.x;
    const int m0   = blockIdx.x * 128;
    const int n0   = blockIdx.y * 128;
    const int lane = t & 63;
    const int wave = t >> 6;
    const int wr   = (wave >> 1) * 64;   // wave row base in tile
    const int wc   = (wave & 1) * 64;    // wave col base in tile
    const int lr   = lane & 15;
    const int kg   = lane >> 4;          // k-group 0..3

    // staging: wave stages rows [wave*32, wave*32+32) of each tile, 2 insts x 16 rows
    const int lrow  = lane >> 2;         // row within a 16-row instruction
    const int lch   = lane & 3;          // 16B chunk within the 64B row
    const int srow0 = wave * 32;

    f32x4 acc[4][4];
#pragma unroll
    for (int i = 0; i < 4; ++i)
#pragma unroll
        for (int j = 0; j < 4; ++j) acc[i][j] = (f32x4)(0.0f);

    for (int k0 = 0; k0 < D256; k0 += 32) {
        __syncthreads();   // previous tile's reads done before overwrite
#pragma unroll
        for (int i = 0; i < 2; ++i) {
            const int r   = srow0 + i * 16;
            const int ar  = m0 + r + lrow;
            const int arc = ar < M ? ar : (M - 1);          // clamp tail rows
            const size_t ga = (size_t)arc * D256 + k0 + lch * 8;
            const size_t gb = (size_t)(n0 + r + lrow) * D256 + k0 + lch * 8;
            GLOAD16(A + ga, As + r * 32);
            GLOAD16(Bt + gb, Bs + r * 32);
            if (DUAL) {
                GLOAD16(A2 + ga, A2s + r * 32);
                GLOAD16(Bt2 + gb, B2s + r * 32);
            }
        }
        __syncthreads();   // compiler drains vmcnt(0) before barrier

        bf16x8 af[4], bf[4];
#pragma unroll
        for (int mi = 0; mi < 4; ++mi)
            af[mi] = *(const bf16x8*)&As[(wr + mi * 16 + lr) * 32 + kg * 8];
#pragma unroll
        for (int ni = 0; ni < 4; ++ni)
            bf[ni] = *(const bf16x8*)&Bs[(wc + ni * 16 + lr) * 32 + kg * 8];
#pragma unroll
        for (int mi = 0; mi < 4; ++mi)
#pragma unroll
            for (int ni = 0; ni < 4; ++ni)
                acc[mi][ni] = __builtin_amdgcn_mfma_f32_16x16x32_bf16(
                    af[mi], bf[ni], acc[mi][ni], 0, 0, 0);
        if (DUAL) {
            bf16x8 af2[4], bf2[4];
#pragma unroll
            for (int mi = 0; mi < 4; ++mi)
                af2[mi] = *(const bf16x8*)&A2s[(wr + mi * 16 + lr) * 32 + kg * 8];
#pragma unroll
            for (int ni = 0; ni < 4; ++ni)
                bf2[ni] = *(const bf16x8*)&B2s[(wc + ni * 16 + lr) * 32 + kg * 8];
#pragma unroll
            for (int mi = 0; mi < 4; ++mi)
#pragma unroll
                for (int ni = 0; ni < 4; ++ni)
                    acc[mi][ni] = __builtin_amdgcn_mfma_f32_16x16x32_bf16(
                        af2[mi], bf2[ni], acc[mi][ni], 0, 0, 0);
        }
    }

    // C/D layout: col = lane&15, row = (lane>>4)*4 + j
#pragma unroll
    for (int ni = 0; ni < 4; ++ni) {
        const int col = n0 + wc + ni * 16 + lr;
        const float bb = bias[col];
#pragma unroll
        for (int mi = 0; mi < 4; ++mi) {
            const int rbase = m0 + wr + mi * 16 + kg * 4;
#pragma unroll
            for (int j = 0; j < 4; ++j) {
                const int row = rbase + j;
                if (row < M) {
                    float v = acc[mi][ni][j] + bb;
                    if (RELU) v = fmaxf(v, 0.0f);
                    if (OUT_BF16)
                        ((ushort*)outp)[(size_t)row * D256 + col] = f2bf(v);
                    else
                        ((float*)outp)[(size_t)row * D256 + col] = v;
                }
            }
        }
    }
}

// ---------------- fp32 -> bf16 convert ----------------
__global__ __launch_bounds__(256)
void f2bf_kernel(const float* __restrict__ in, ushort* __restrict__ out, int n4)
{
    const int i = blockIdx.x * 256 + threadIdx.x;
    if (i >= n4) return;
    const float4 v = ((const float4*)in)[i];
    ushort4 o;
    o.x = f2bf(v.x); o.y = f2bf(v.y); o.z = f2bf(v.z); o.w = f2bf(v.w);
    ((ushort4*)out)[i] = o;
}

// ---------------- weight transpose+convert: Bt[n][k] = bf16(W[k][n]) ----------------
struct WP  { const float* w; ushort* o; };
struct WP6 { WP p[6]; };
__global__ __launch_bounds__(256)
void wtrans_kernel(WP6 ps)
{
    const float* __restrict__ W = ps.p[blockIdx.z].w;
    ushort* __restrict__ O      = ps.p[blockIdx.z].o;
    __shared__ float sm[32][33];
    const int tx = threadIdx.x & 31, ty = threadIdx.x >> 5;
    const int k0 = blockIdx.x * 32, n0 = blockIdx.y * 32;
#pragma unroll
    for (int i = 0; i < 4; ++i)
        sm[ty + i * 8][tx] = W[(size_t)(k0 + ty + i * 8) * D256 + n0 + tx];
    __syncthreads();
#pragma unroll
    for (int i = 0; i < 4; ++i)
        O[(size_t)(n0 + ty + i * 8) * D256 + k0 + tx] = f2bf(sm[tx][ty + i * 8]);
}

// ---------------- CSR build: histogram -> hierarchical scan -> bucket scatter ----------------
__global__ __launch_bounds__(256)
void hist_kernel(const int* __restrict__ dst, int* __restrict__ deg, int E)
{
    const int stride = gridDim.x * 256;
    for (int e = blockIdx.x * 256 + threadIdx.x; e < E; e += stride)
        atomicAdd(&deg[dst[e]], 1);
}

// per-block (1024 elems) inclusive scan: wave shfl scan + 16-wave LDS combine
__global__ __launch_bounds__(1024)
void blockscan_kernel(const int* __restrict__ deg, int* __restrict__ incl,
                      int* __restrict__ partials, int N)
{
    __shared__ int wt[16];
    const int i    = blockIdx.x * 1024 + threadIdx.x;
    const int lane = threadIdx.x & 63;
    const int wv   = threadIdx.x >> 6;
    const int v    = (i < N) ? deg[i] : 0;
    int s = v;
#pragma unroll
    for (int o = 1; o < 64; o <<= 1) {
        const int t = __shfl_up(s, o);
        if (lane >= o) s += t;
    }
    if (lane == 63) wt[wv] = s;
    __syncthreads();
    if (wv == 0 && lane < 16) {
        const int w = wt[lane];
        int ws = w;
#pragma unroll
        for (int o = 1; o < 16; o <<= 1) {
            const int t = __shfl_up(ws, o);
            if (lane >= o) ws += t;
        }
        wt[lane] = ws - w;   // exclusive wave offset
    }
    __syncthreads();
    s += wt[wv];
    if (i < N) incl[i] = s;
    if (threadIdx.x == 1023) partials[blockIdx.x] = s;
}

// scan the (<=1024) block totals into exclusive offsets; single block
__global__ __launch_bounds__(1024)
void scanp_kernel(int* __restrict__ partials, int nb)
{
    __shared__ int sm[1024];
    const int v = (threadIdx.x < (unsigned)nb) ? partials[threadIdx.x] : 0;
    sm[threadIdx.x] = v;
    __syncthreads();
#pragma unroll
    for (int off = 1; off < 1024; off <<= 1) {
        const int t = (threadIdx.x >= (unsigned)off) ? sm[threadIdx.x - off] : 0;
        __syncthreads();
        sm[threadIdx.x] += t;
        __syncthreads();
    }
    if (threadIdx.x < (unsigned)nb) partials[threadIdx.x] = sm[threadIdx.x] - v;
}

__global__ __launch_bounds__(1024)
void finalize_kernel(const int* __restrict__ deg, const int* __restrict__ incl,
                     const int* __restrict__ partials, int* __restrict__ row_ptr,
                     int* __restrict__ cursor, int N, int E)
{
    const int i = blockIdx.x * 1024 + threadIdx.x;
    if (i < N) {
        const int ex = partials[blockIdx.x] + incl[i] - deg[i];
        row_ptr[i] = ex;
        cursor[i]  = ex;
    }
    if (i == 0) row_ptr[N] = E;
}

__global__ __launch_bounds__(256)
void bucket_kernel(const int* __restrict__ src, const int* __restrict__ dst,
                   int* __restrict__ cursor, int* __restrict__ esrc, int E)
{
    const int stride = gridDim.x * 256;
    for (int e = blockIdx.x * 256 + threadIdx.x; e < E; e += stride) {
        const int p = atomicAdd(&cursor[dst[e]], 1);
        esrc[p] = src[e];
    }
}

// ---------------- node-parallel segment max over bf16 rows ----------------
// m >= 0 (relu), so unsigned-short compare == float compare; 0 = identity.
__global__ __launch_bounds__(256)
void agg_max_kernel(const int* __restrict__ row_ptr, const int* __restrict__ esrc,
                    const ushort* __restrict__ m, ushort* __restrict__ agg, int N)
{
    const int wid  = (int)(((size_t)blockIdx.x * 256 + threadIdx.x) >> 6);
    const int lane = threadIdx.x & 63;
    if (wid >= N) return;
    const int beg = row_ptr[wid];
    const int end = row_ptr[wid + 1];
    const size_t off = (size_t)(lane * 4);

    ushort4 a0 = make_ushort4(0, 0, 0, 0);
    ushort4 a1 = a0, a2 = a0, a3 = a0;
    int e = beg;
    for (; e + 8 <= end; e += 8) {
        int s[8];
#pragma unroll
        for (int q = 0; q < 8; ++q) s[q] = esrc[e + q];
        ushort4 v[8];
#pragma unroll
        for (int q = 0; q < 8; ++q)
            v[q] = *(const ushort4*)(m + (size_t)s[q] * D256 + off);
        a0 = vmax4(a0, vmax4(v[0], v[4]));
        a1 = vmax4(a1, vmax4(v[1], v[5]));
        a2 = vmax4(a2, vmax4(v[2], v[6]));
        a3 = vmax4(a3, vmax4(v[3], v[7]));
    }
    for (; e + 2 <= end; e += 2) {
        const int s0 = esrc[e];
        const int s1 = esrc[e + 1];
        const ushort4 v0 = *(const ushort4*)(m + (size_t)s0 * D256 + off);
        const ushort4 v1 = *(const ushort4*)(m + (size_t)s1 * D256 + off);
        a0 = vmax4(a0, v0);
        a1 = vmax4(a1, v1);
    }
    if (e < end) {
        const ushort4 v0 = *(const ushort4*)(m + (size_t)esrc[e] * D256 + off);
        a2 = vmax4(a2, v0);
    }
    const ushort4 r = vmax4(vmax4(a0, a1), vmax4(a2, a3));
    *(ushort4*)(agg + (size_t)wid * D256 + off) = r;
}

// ------------- row-wise L2 normalize: fp32 out + bf16 copy -------------
__global__ __launch_bounds__(256)
void l2norm_kernel(const float* __restrict__ in, float* __restrict__ out_f,
                   ushort* __restrict__ out_b, int M)
{
    const int wid  = (int)(((size_t)blockIdx.x * 256 + threadIdx.x) >> 6);
    const int lane = threadIdx.x & 63;
    if (wid >= M) return;
    const float4 v = *(const float4*)(in + (size_t)wid * D256 + lane * 4);
    float ss = v.x * v.x + v.y * v.y + v.z * v.z + v.w * v.w;
#pragma unroll
    for (int o = 32; o >= 1; o >>= 1) ss += __shfl_xor(ss, o);
    const float inv = 1.0f / fmaxf(sqrtf(ss), 1e-12f);
    float4 o4;
    o4.x = v.x * inv; o4.y = v.y * inv; o4.z = v.z * inv; o4.w = v.w * inv;
    *(float4*)(out_f + (size_t)wid * D256 + lane * 4) = o4;
    ushort4 ob;
    ob.x = f2bf(o4.x); ob.y = f2bf(o4.y); ob.z = f2bf(o4.z); ob.w = f2bf(o4.w);
    *(ushort4*)(out_b + (size_t)wid * D256 + lane * 4) = ob;
}

extern "C" void kernel_launch(void* const* d_in, const int* in_sizes, int n_in,
                              void* d_out, int out_size, void* d_ws, size_t ws_size,
                              hipStream_t stream)
{
    const float* x        = (const float*)d_in[0];
    const int*   src      = (const int*)  d_in[1];
    const int*   dst      = (const int*)  d_in[2];
    const float* W_pool0  = (const float*)d_in[3];
    const float* b_pool0  = (const float*)d_in[4];
    const float* W_self0  = (const float*)d_in[5];
    const float* W_neigh0 = (const float*)d_in[6];
    const float* b0       = (const float*)d_in[7];
    const float* W_pool1  = (const float*)d_in[8];
    const float* b_pool1  = (const float*)d_in[9];
    const float* W_self1  = (const float*)d_in[10];
    const float* W_neigh1 = (const float*)d_in[11];
    const float* b1       = (const float*)d_in[12];

    const int N = in_sizes[0] / D256;
    const int E = in_sizes[1];
    const size_t NR = (size_t)N * D256;   // elems per node matrix

    float* h1  = (float*)d_out;                     // [N,256] layer-1 out (fp32)
    float* enc = (float*)d_out + NR;                // [N,256] enc_feat_input (fp32)

    // workspace layout
    ushort* xb   = (ushort*)d_ws;                   // bf16 A (x for L0, enc for L1)
    ushort* mb   = xb + NR;                         // bf16 pool msgs
    ushort* aggb = mb + NR;                         // bf16 aggregated
    float*  tmp  = (float*)(aggb + NR);             // fp32 pre-norm h0
    ushort* Bt   = (ushort*)(tmp + NR);             // 6 x [256,256] bf16 W^T
    int* row_ptr = (int*)(Bt + 6 * 256 * 256);      // N+1
    int* cursor  = row_ptr + (N + 1);
    int* deg     = cursor + N;
    int* incl    = deg + N;                         // N (inclusive scan scratch)
    int* partials= incl + N;                        // <=1024
    int* esrc    = partials + 1024;                 // E

    ushort* Bt_pool0  = Bt + 0 * 65536;
    ushort* Bt_self0  = Bt + 1 * 65536;
    ushort* Bt_neigh0 = Bt + 2 * 65536;
    ushort* Bt_pool1  = Bt + 3 * 65536;
    ushort* Bt_self1  = Bt + 4 * 65536;
    ushort* Bt_neigh1 = Bt + 5 * 65536;

    const dim3 gemm_grid((N + 127) / 128, 2);
    const int  edge_blocks = (E + 255) / 256 < 2048 ? (E + 255) / 256 : 2048;
    const int  node_blocks = (N + 3) / 4;
    const int  conv_blocks = (int)((NR / 4 + 255) / 256);
    const int  scan_blocks = (N + 1023) / 1024;

    // ---------------- one-time conversions ----------------
    WP6 wp;
    wp.p[0] = { W_pool0,  Bt_pool0  };
    wp.p[1] = { W_self0,  Bt_self0  };
    wp.p[2] = { W_neigh0, Bt_neigh0 };
    wp.p[3] = { W_pool1,  Bt_pool1  };
    wp.p[4] = { W_self1,  Bt_self1  };
    wp.p[5] = { W_neigh1, Bt_neigh1 };
    wtrans_kernel<<<dim3(8, 8, 6), 256, 0, stream>>>(wp);
    f2bf_kernel<<<conv_blocks, 256, 0, stream>>>(x, xb, (int)(NR / 4));

    // ---------------- CSR build ----------------
    hipMemsetAsync(deg, 0, (size_t)N * sizeof(int), stream);
    hist_kernel<<<edge_blocks, 256, 0, stream>>>(dst, deg, E);
    blockscan_kernel<<<scan_blocks, 1024, 0, stream>>>(deg, incl, partials, N);
    scanp_kernel<<<1, 1024, 0, stream>>>(partials, scan_blocks);
    finalize_kernel<<<scan_blocks, 1024, 0, stream>>>(deg, incl, partials,
                                                      row_ptr, cursor, N, E);
    bucket_kernel<<<edge_blocks, 256, 0, stream>>>(src, dst, cursor, esrc, E);

    // ---------------- layer 0 ----------------
    mfma_gemm_kernel<0,1,1><<<gemm_grid, 256, 0, stream>>>(xb, Bt_pool0, nullptr, nullptr,
                                                           b_pool0, mb, N);
    agg_max_kernel<<<node_blocks, 256, 0, stream>>>(row_ptr, esrc, mb, aggb, N);
    mfma_gemm_kernel<1,1,0><<<gemm_grid, 256, 0, stream>>>(xb, Bt_self0, aggb, Bt_neigh0,
                                                           b0, tmp, N);
    l2norm_kernel<<<node_blocks, 256, 0, stream>>>(tmp, enc, xb, N);  // xb now holds enc bf16

    // ---------------- layer 1 ----------------
    mfma_gemm_kernel<0,1,1><<<gemm_grid, 256, 0, stream>>>(xb, Bt_pool1, nullptr, nullptr,
                                                           b_pool1, mb, N);
    agg_max_kernel<<<node_blocks, 256, 0, stream>>>(row_ptr, esrc, mb, aggb, N);
    mfma_gemm_kernel<1,0,0><<<gemm_grid, 256, 0, stream>>>(xb, Bt_self1, aggb, Bt_neigh1,
                                                           b1, h1, N);
}

// Round 7
// 373.734 us; speedup vs baseline: 6.4273x; 1.0335x over previous
//
#include <hip/hip_runtime.h>
#include <cstddef>

#define D256 256

typedef __attribute__((ext_vector_type(8))) short bf16x8;
typedef __attribute__((ext_vector_type(4))) float f32x4;

// global -> LDS direct (16B per lane, wave-uniform LDS base + lane*16)
#define GLOAD16(gptr, lptr)                                                         \
    __builtin_amdgcn_global_load_lds(                                               \
        (const __attribute__((address_space(1))) unsigned int*)(gptr),              \
        (__attribute__((address_space(3))) unsigned int*)(lptr), 16, 0, 0)

__device__ __forceinline__ ushort f2bf(float f) {
    unsigned u = __float_as_uint(f);
    return (ushort)((u + 0x7FFFu + ((u >> 16) & 1u)) >> 16);   // RNE
}
__device__ __forceinline__ ushort umax16(ushort a, ushort b) { return a > b ? a : b; }
__device__ __forceinline__ ushort4 vmax4(ushort4 a, ushort4 b) {
    return make_ushort4(umax16(a.x, b.x), umax16(a.y, b.y),
                        umax16(a.z, b.z), umax16(a.w, b.w));
}

// ---------------- MFMA GEMM: out = act( A@Bt^T (+ A2@Bt2^T) + bias ) ----------------
// A [M,256] bf16 row-major; Bt [256,256] bf16 = W^T (row n = output col, K-contiguous).
// 128x128 tile, 4 waves (2x2), 64x64/wave, BK=32, 16x16x32 MFMA.
// Staging via global_load_lds dwordx4 into LINEAR LDS [row][32]; fragment
// ds_read_b128 at 64B row-stride = 2 lanes/bank = conflict-free (m136).
// SWAPPED-OPERAND mfma(bf, af): D frag holds (m = lane&15, n = kg*4 + reg)
// -> 4 consecutive n per lane -> float4/ushort4 epilogue stores (4x fewer insts).
template<int DUAL, int RELU, int OUT_BF16>
__global__ __launch_bounds__(256)
void mfma_gemm_kernel(const ushort* __restrict__ A, const ushort* __restrict__ Bt,
                      const ushort* __restrict__ A2, const ushort* __restrict__ Bt2,
                      const float* __restrict__ bias, void* __restrict__ outp, int M)
{
    __shared__ ushort smem[(DUAL ? 4 : 2) * 128 * 32];
    ushort* const As  = smem;
    ushort* const Bs  = smem + 4096;
    ushort* const A2s = smem + (DUAL ? 8192 : 0);
    ushort* const B2s = smem + (DUAL ? 12288 : 0);

    const int t    = threadIdx.x;
    const int m0   = blockIdx.x * 128;
    const int n0   = blockIdx.y * 128;
    const int lane = t & 63;
    const int wave = t >> 6;
    const int wr   = (wave >> 1) * 64;   // wave row base in tile
    const int wc   = (wave & 1) * 64;    // wave col base in tile
    const int lr   = lane & 15;
    const int kg   = lane >> 4;          // k-group 0..3

    // staging: wave stages rows [wave*32, wave*32+32) of each tile, 2 insts x 16 rows
    const int lrow  = lane >> 2;         // row within a 16-row instruction
    const int lch   = lane & 3;          // 16B chunk within the 64B row
    const int srow0 = wave * 32;

    f32x4 acc[4][4];
#pragma unroll
    for (int i = 0; i < 4; ++i)
#pragma unroll
        for (int j = 0; j < 4; ++j) acc[i][j] = (f32x4)(0.0f);

    for (int k0 = 0; k0 < D256; k0 += 32) {
        __syncthreads();   // previous tile's reads done before overwrite
#pragma unroll
        for (int i = 0; i < 2; ++i) {
            const int r   = srow0 + i * 16;
            const int ar  = m0 + r + lrow;
            const int arc = ar < M ? ar : (M - 1);          // clamp tail rows
            const size_t ga = (size_t)arc * D256 + k0 + lch * 8;
            const size_t gb = (size_t)(n0 + r + lrow) * D256 + k0 + lch * 8;
            GLOAD16(A + ga, As + r * 32);
            GLOAD16(Bt + gb, Bs + r * 32);
            if (DUAL) {
                GLOAD16(A2 + ga, A2s + r * 32);
                GLOAD16(Bt2 + gb, B2s + r * 32);
            }
        }
        __syncthreads();   // compiler drains vmcnt(0) before barrier

        bf16x8 af[4], bf[4];
#pragma unroll
        for (int mi = 0; mi < 4; ++mi)
            af[mi] = *(const bf16x8*)&As[(wr + mi * 16 + lr) * 32 + kg * 8];
#pragma unroll
        for (int ni = 0; ni < 4; ++ni)
            bf[ni] = *(const bf16x8*)&Bs[(wc + ni * 16 + lr) * 32 + kg * 8];
#pragma unroll
        for (int mi = 0; mi < 4; ++mi)
#pragma unroll
            for (int ni = 0; ni < 4; ++ni)
                acc[mi][ni] = __builtin_amdgcn_mfma_f32_16x16x32_bf16(
                    bf[ni], af[mi], acc[mi][ni], 0, 0, 0);   // swapped operands
        if (DUAL) {
            bf16x8 af2[4], bf2[4];
#pragma unroll
            for (int mi = 0; mi < 4; ++mi)
                af2[mi] = *(const bf16x8*)&A2s[(wr + mi * 16 + lr) * 32 + kg * 8];
#pragma unroll
            for (int ni = 0; ni < 4; ++ni)
                bf2[ni] = *(const bf16x8*)&B2s[(wc + ni * 16 + lr) * 32 + kg * 8];
#pragma unroll
            for (int mi = 0; mi < 4; ++mi)
#pragma unroll
                for (int ni = 0; ni < 4; ++ni)
                    acc[mi][ni] = __builtin_amdgcn_mfma_f32_16x16x32_bf16(
                        bf2[ni], af2[mi], acc[mi][ni], 0, 0, 0);
        }
    }

    // Swapped C/D layout: m = lane&15, n = kg*4 + reg  -> vector stores
#pragma unroll
    for (int ni = 0; ni < 4; ++ni) {
        const int colb = n0 + wc + ni * 16 + kg * 4;
        const float4 bb = *(const float4*)(bias + colb);
#pragma unroll
        for (int mi = 0; mi < 4; ++mi) {
            const int row = m0 + wr + mi * 16 + lr;
            if (row < M) {
                const f32x4 a = acc[mi][ni];
                float4 o;
                o.x = a[0] + bb.x;
                o.y = a[1] + bb.y;
                o.z = a[2] + bb.z;
                o.w = a[3] + bb.w;
                if (RELU) {
                    o.x = fmaxf(o.x, 0.f); o.y = fmaxf(o.y, 0.f);
                    o.z = fmaxf(o.z, 0.f); o.w = fmaxf(o.w, 0.f);
                }
                if (OUT_BF16) {
                    ushort4 ob;
                    ob.x = f2bf(o.x); ob.y = f2bf(o.y);
                    ob.z = f2bf(o.z); ob.w = f2bf(o.w);
                    *(ushort4*)((ushort*)outp + (size_t)row * D256 + colb) = ob;
                } else {
                    *(float4*)((float*)outp + (size_t)row * D256 + colb) = o;
                }
            }
        }
    }
}

// ---------------- fp32 -> bf16 convert ----------------
__global__ __launch_bounds__(256)
void f2bf_kernel(const float* __restrict__ in, ushort* __restrict__ out, int n4)
{
    const int i = blockIdx.x * 256 + threadIdx.x;
    if (i >= n4) return;
    const float4 v = ((const float4*)in)[i];
    ushort4 o;
    o.x = f2bf(v.x); o.y = f2bf(v.y); o.z = f2bf(v.z); o.w = f2bf(v.w);
    ((ushort4*)out)[i] = o;
}

// ---------------- weight transpose+convert: Bt[n][k] = bf16(W[k][n]) ----------------
struct WP  { const float* w; ushort* o; };
struct WP6 { WP p[6]; };
__global__ __launch_bounds__(256)
void wtrans_kernel(WP6 ps)
{
    const float* __restrict__ W = ps.p[blockIdx.z].w;
    ushort* __restrict__ O      = ps.p[blockIdx.z].o;
    __shared__ float sm[32][33];
    const int tx = threadIdx.x & 31, ty = threadIdx.x >> 5;
    const int k0 = blockIdx.x * 32, n0 = blockIdx.y * 32;
#pragma unroll
    for (int i = 0; i < 4; ++i)
        sm[ty + i * 8][tx] = W[(size_t)(k0 + ty + i * 8) * D256 + n0 + tx];
    __syncthreads();
#pragma unroll
    for (int i = 0; i < 4; ++i)
        O[(size_t)(n0 + ty + i * 8) * D256 + k0 + tx] = f2bf(sm[tx][ty + i * 8]);
}

// ---------------- CSR build: histogram -> hierarchical scan -> bucket scatter ----------------
__global__ __launch_bounds__(256)
void hist_kernel(const int* __restrict__ dst, int* __restrict__ deg, int E)
{
    const int stride = gridDim.x * 256;
    for (int e = blockIdx.x * 256 + threadIdx.x; e < E; e += stride)
        atomicAdd(&deg[dst[e]], 1);
}

// per-block (1024 elems) inclusive scan: wave shfl scan + 16-wave LDS combine
__global__ __launch_bounds__(1024)
void blockscan_kernel(const int* __restrict__ deg, int* __restrict__ incl,
                      int* __restrict__ partials, int N)
{
    __shared__ int wt[16];
    const int i    = blockIdx.x * 1024 + threadIdx.x;
    const int lane = threadIdx.x & 63;
    const int wv   = threadIdx.x >> 6;
    const int v    = (i < N) ? deg[i] : 0;
    int s = v;
#pragma unroll
    for (int o = 1; o < 64; o <<= 1) {
        const int t = __shfl_up(s, o);
        if (lane >= o) s += t;
    }
    if (lane == 63) wt[wv] = s;
    __syncthreads();
    if (wv == 0 && lane < 16) {
        const int w = wt[lane];
        int ws = w;
#pragma unroll
        for (int o = 1; o < 16; o <<= 1) {
            const int t = __shfl_up(ws, o);
            if (lane >= o) ws += t;
        }
        wt[lane] = ws - w;   // exclusive wave offset
    }
    __syncthreads();
    s += wt[wv];
    if (i < N) incl[i] = s;
    if (threadIdx.x == 1023) partials[blockIdx.x] = s;
}

// scan the (<=1024) block totals into exclusive offsets; single block
__global__ __launch_bounds__(1024)
void scanp_kernel(int* __restrict__ partials, int nb)
{
    __shared__ int sm[1024];
    const int v = (threadIdx.x < (unsigned)nb) ? partials[threadIdx.x] : 0;
    sm[threadIdx.x] = v;
    __syncthreads();
#pragma unroll
    for (int off = 1; off < 1024; off <<= 1) {
        const int t = (threadIdx.x >= (unsigned)off) ? sm[threadIdx.x - off] : 0;
        __syncthreads();
        sm[threadIdx.x] += t;
        __syncthreads();
    }
    if (threadIdx.x < (unsigned)nb) partials[threadIdx.x] = sm[threadIdx.x] - v;
}

__global__ __launch_bounds__(1024)
void finalize_kernel(const int* __restrict__ deg, const int* __restrict__ incl,
                     const int* __restrict__ partials, int* __restrict__ row_ptr,
                     int* __restrict__ cursor, int N, int E)
{
    const int i = blockIdx.x * 1024 + threadIdx.x;
    if (i < N) {
        const int ex = partials[blockIdx.x] + incl[i] - deg[i];
        row_ptr[i] = ex;
        cursor[i]  = ex;
    }
    if (i == 0) row_ptr[N] = E;
}

__global__ __launch_bounds__(256)
void bucket_kernel(const int* __restrict__ src, const int* __restrict__ dst,
                   int* __restrict__ cursor, int* __restrict__ esrc, int E)
{
    const int stride = gridDim.x * 256;
    for (int e = blockIdx.x * 256 + threadIdx.x; e < E; e += stride) {
        const int p = atomicAdd(&cursor[dst[e]], 1);
        esrc[p] = src[e];
    }
}

// ---------------- node-parallel segment max over bf16 rows ----------------
// m >= 0 (relu), so unsigned-short compare == float compare; 0 = identity.
__global__ __launch_bounds__(256)
void agg_max_kernel(const int* __restrict__ row_ptr, const int* __restrict__ esrc,
                    const ushort* __restrict__ m, ushort* __restrict__ agg, int N)
{
    const int wid  = (int)(((size_t)blockIdx.x * 256 + threadIdx.x) >> 6);
    const int lane = threadIdx.x & 63;
    if (wid >= N) return;
    const int beg = row_ptr[wid];
    const int end = row_ptr[wid + 1];
    const size_t off = (size_t)(lane * 4);

    ushort4 a0 = make_ushort4(0, 0, 0, 0);
    ushort4 a1 = a0, a2 = a0, a3 = a0;
    int e = beg;
    for (; e + 8 <= end; e += 8) {
        int s[8];
#pragma unroll
        for (int q = 0; q < 8; ++q) s[q] = esrc[e + q];
        ushort4 v[8];
#pragma unroll
        for (int q = 0; q < 8; ++q)
            v[q] = *(const ushort4*)(m + (size_t)s[q] * D256 + off);
        a0 = vmax4(a0, vmax4(v[0], v[4]));
        a1 = vmax4(a1, vmax4(v[1], v[5]));
        a2 = vmax4(a2, vmax4(v[2], v[6]));
        a3 = vmax4(a3, vmax4(v[3], v[7]));
    }
    for (; e + 2 <= end; e += 2) {
        const int s0 = esrc[e];
        const int s1 = esrc[e + 1];
        const ushort4 v0 = *(const ushort4*)(m + (size_t)s0 * D256 + off);
        const ushort4 v1 = *(const ushort4*)(m + (size_t)s1 * D256 + off);
        a0 = vmax4(a0, v0);
        a1 = vmax4(a1, v1);
    }
    if (e < end) {
        const ushort4 v0 = *(const ushort4*)(m + (size_t)esrc[e] * D256 + off);
        a2 = vmax4(a2, v0);
    }
    const ushort4 r = vmax4(vmax4(a0, a1), vmax4(a2, a3));
    *(ushort4*)(agg + (size_t)wid * D256 + off) = r;
}

// ------------- row-wise L2 normalize: fp32 out + bf16 copy -------------
__global__ __launch_bounds__(256)
void l2norm_kernel(const float* __restrict__ in, float* __restrict__ out_f,
                   ushort* __restrict__ out_b, int M)
{
    const int wid  = (int)(((size_t)blockIdx.x * 256 + threadIdx.x) >> 6);
    const int lane = threadIdx.x & 63;
    if (wid >= M) return;
    const float4 v = *(const float4*)(in + (size_t)wid * D256 + lane * 4);
    float ss = v.x * v.x + v.y * v.y + v.z * v.z + v.w * v.w;
#pragma unroll
    for (int o = 32; o >= 1; o >>= 1) ss += __shfl_xor(ss, o);
    const float inv = 1.0f / fmaxf(sqrtf(ss), 1e-12f);
    float4 o4;
    o4.x = v.x * inv; o4.y = v.y * inv; o4.z = v.z * inv; o4.w = v.w * inv;
    *(float4*)(out_f + (size_t)wid * D256 + lane * 4) = o4;
    ushort4 ob;
    ob.x = f2bf(o4.x); ob.y = f2bf(o4.y); ob.z = f2bf(o4.z); ob.w = f2bf(o4.w);
    *(ushort4*)(out_b + (size_t)wid * D256 + lane * 4) = ob;
}

extern "C" void kernel_launch(void* const* d_in, const int* in_sizes, int n_in,
                              void* d_out, int out_size, void* d_ws, size_t ws_size,
                              hipStream_t stream)
{
    const float* x        = (const float*)d_in[0];
    const int*   src      = (const int*)  d_in[1];
    const int*   dst      = (const int*)  d_in[2];
    const float* W_pool0  = (const float*)d_in[3];
    const float* b_pool0  = (const float*)d_in[4];
    const float* W_self0  = (const float*)d_in[5];
    const float* W_neigh0 = (const float*)d_in[6];
    const float* b0       = (const float*)d_in[7];
    const float* W_pool1  = (const float*)d_in[8];
    const float* b_pool1  = (const float*)d_in[9];
    const float* W_self1  = (const float*)d_in[10];
    const float* W_neigh1 = (const float*)d_in[11];
    const float* b1       = (const float*)d_in[12];

    const int N = in_sizes[0] / D256;
    const int E = in_sizes[1];
    const size_t NR = (size_t)N * D256;   // elems per node matrix

    float* h1  = (float*)d_out;                     // [N,256] layer-1 out (fp32)
    float* enc = (float*)d_out + NR;                // [N,256] enc_feat_input (fp32)

    // workspace layout
    ushort* xb   = (ushort*)d_ws;                   // bf16 A (x for L0, enc for L1)
    ushort* mb   = xb + NR;                         // bf16 pool msgs
    ushort* aggb = mb + NR;                         // bf16 aggregated
    float*  tmp  = (float*)(aggb + NR);             // fp32 pre-norm h0
    ushort* Bt   = (ushort*)(tmp + NR);             // 6 x [256,256] bf16 W^T
    int* row_ptr = (int*)(Bt + 6 * 256 * 256);      // N+1
    int* cursor  = row_ptr + (N + 1);
    int* deg     = cursor + N;
    int* incl    = deg + N;                         // N (inclusive scan scratch)
    int* partials= incl + N;                        // <=1024
    int* esrc    = partials + 1024;                 // E

    ushort* Bt_pool0  = Bt + 0 * 65536;
    ushort* Bt_self0  = Bt + 1 * 65536;
    ushort* Bt_neigh0 = Bt + 2 * 65536;
    ushort* Bt_pool1  = Bt + 3 * 65536;
    ushort* Bt_self1  = Bt + 4 * 65536;
    ushort* Bt_neigh1 = Bt + 5 * 65536;

    const dim3 gemm_grid((N + 127) / 128, 2);
    const int  edge_blocks = (E + 255) / 256 < 2048 ? (E + 255) / 256 : 2048;
    const int  node_blocks = (N + 3) / 4;
    const int  conv_blocks = (int)((NR / 4 + 255) / 256);
    const int  scan_blocks = (N + 1023) / 1024;

    // ---------------- one-time conversions ----------------
    WP6 wp;
    wp.p[0] = { W_pool0,  Bt_pool0  };
    wp.p[1] = { W_self0,  Bt_self0  };
    wp.p[2] = { W_neigh0, Bt_neigh0 };
    wp.p[3] = { W_pool1,  Bt_pool1  };
    wp.p[4] = { W_self1,  Bt_self1  };
    wp.p[5] = { W_neigh1, Bt_neigh1 };
    wtrans_kernel<<<dim3(8, 8, 6), 256, 0, stream>>>(wp);
    f2bf_kernel<<<conv_blocks, 256, 0, stream>>>(x, xb, (int)(NR / 4));

    // ---------------- CSR build ----------------
    hipMemsetAsync(deg, 0, (size_t)N * sizeof(int), stream);
    hist_kernel<<<edge_blocks, 256, 0, stream>>>(dst, deg, E);
    blockscan_kernel<<<scan_blocks, 1024, 0, stream>>>(deg, incl, partials, N);
    scanp_kernel<<<1, 1024, 0, stream>>>(partials, scan_blocks);
    finalize_kernel<<<scan_blocks, 1024, 0, stream>>>(deg, incl, partials,
                                                      row_ptr, cursor, N, E);
    bucket_kernel<<<edge_blocks, 256, 0, stream>>>(src, dst, cursor, esrc, E);

    // ---------------- layer 0 ----------------
    mfma_gemm_kernel<0,1,1><<<gemm_grid, 256, 0, stream>>>(xb, Bt_pool0, nullptr, nullptr,
                                                           b_pool0, mb, N);
    agg_max_kernel<<<node_blocks, 256, 0, stream>>>(row_ptr, esrc, mb, aggb, N);
    mfma_gemm_kernel<1,1,0><<<gemm_grid, 256, 0, stream>>>(xb, Bt_self0, aggb, Bt_neigh0,
                                                           b0, tmp, N);
    l2norm_kernel<<<node_blocks, 256, 0, stream>>>(tmp, enc, xb, N);  // xb now holds enc bf16

    // ---------------- layer 1 ----------------
    mfma_gemm_kernel<0,1,1><<<gemm_grid, 256, 0, stream>>>(xb, Bt_pool1, nullptr, nullptr,
                                                           b_pool1, mb, N);
    agg_max_kernel<<<node_blocks, 256, 0, stream>>>(row_ptr, esrc, mb, aggb, N);
    mfma_gemm_kernel<1,0,0><<<gemm_grid, 256, 0, stream>>>(xb, Bt_self1, aggb, Bt_neigh1,
                                                           b1, h1, N);
}